// Round 1
// baseline (1989.885 us; speedup 1.0000x reference)
//
#include <hip/hip_runtime.h>

// ---------------- problem constants ----------------
constexpr int Nn   = 100000;
constexpr int Ne   = 1600000;
constexpr int FINN = 64;
constexpr int Dh   = 20;
constexpr int Dout = 16;
constexpr float EPSV = 1e-5f;

// ---------------- workspace layout (float units) ----------------
constexpr size_t OFF_WC1  = 0;         // 64*40 combined [A|B] layer1
constexpr size_t OFF_C1   = 2560;      // 32
constexpr size_t OFF_WCM  = 2592;      // 3 * 800 (20*40 each)
constexpr size_t OFF_CM   = 4992;      // 3 * 32
constexpr size_t OFF_WC5  = 5088;      // 20*32
constexpr size_t OFF_C5   = 5728;      // 32
constexpr size_t OFF_ST   = 5760;      // 4 layers * 64 (sum@+0, sumsq@+32)
constexpr size_t OFF_OFFS = 8192;      // u32, N+1 (padded 100352)
constexpr size_t OFF_FILL = 108544;    // u32, N   (padded 100352)
constexpr size_t OFF_BSUM = 208896;    // u32, 512
constexpr size_t OFF_CNT  = 209408;    // u32, N (padded 100352)
constexpr size_t OFF_CSR  = 309760;    // u32, Ne  -> ends 1,909,760
constexpr size_t OFF_XA   = 1910784;   // f32, N*20
constexpr size_t OFF_XB   = 3910784;   // f32, N*20
constexpr size_t OFF_HP   = 5910784;   // f32, N*20 -> ends 7,910,784 (~30.2 MiB)

// ---------------- weight folding ----------------
// A = Wl@Wn, B = (Wr+Ws)@Wn, c = (bl+bs)@Wn + bn   (per layer)
__global__ void prep_weights(
    const float* __restrict__ Wl1, const float* __restrict__ bl1,
    const float* __restrict__ Wr1, const float* __restrict__ Ws1,
    const float* __restrict__ bs1, const float* __restrict__ Wn1,
    const float* __restrict__ bn1,
    const float* __restrict__ Wlm, const float* __restrict__ blm,
    const float* __restrict__ Wrm, const float* __restrict__ Wsm,
    const float* __restrict__ bsm, const float* __restrict__ Wnm,
    const float* __restrict__ bnm,
    const float* __restrict__ Wl5, const float* __restrict__ bl5,
    const float* __restrict__ Wr5, const float* __restrict__ Ws5,
    const float* __restrict__ bs5, const float* __restrict__ Wn5,
    const float* __restrict__ bn5,
    float* __restrict__ wc1, float* __restrict__ c1,
    float* __restrict__ wcm, float* __restrict__ cm,
    float* __restrict__ wc5, float* __restrict__ c5)
{
    int layer = blockIdx.x;
    int t = threadIdx.x;
    if (layer == 0) {
        for (int idx = t; idx < FINN * Dh; idx += blockDim.x) {
            int k = idx / Dh, j = idx % Dh;
            float a = 0.f, b = 0.f;
            for (int d = 0; d < Dh; ++d) {
                float wn = Wn1[d * Dh + j];
                a += Wl1[k * Dh + d] * wn;
                b += (Wr1[k * Dh + d] + Ws1[k * Dh + d]) * wn;
            }
            wc1[k * 40 + j] = a;
            wc1[k * 40 + 20 + j] = b;
        }
        for (int j = t; j < Dh; j += blockDim.x) {
            float c0 = 0.f;
            for (int d = 0; d < Dh; ++d) c0 += (bl1[d] + bs1[d]) * Wn1[d * Dh + j];
            c1[j] = c0 + bn1[j];
        }
    } else if (layer <= 3) {
        int i = layer - 1;
        const float* Wl = Wlm + i * Dh * Dh;
        const float* Wr = Wrm + i * Dh * Dh;
        const float* Ws = Wsm + i * Dh * Dh;
        const float* Wn = Wnm + i * Dh * Dh;
        const float* bl = blm + i * Dh;
        const float* bs = bsm + i * Dh;
        const float* bn = bnm + i * Dh;
        float* wc = wcm + i * 800;
        float* cc = cm + i * 32;
        for (int idx = t; idx < Dh * Dh; idx += blockDim.x) {
            int k = idx / Dh, j = idx % Dh;
            float a = 0.f, b = 0.f;
            for (int d = 0; d < Dh; ++d) {
                float wn = Wn[d * Dh + j];
                a += Wl[k * Dh + d] * wn;
                b += (Wr[k * Dh + d] + Ws[k * Dh + d]) * wn;
            }
            wc[k * 40 + j] = a;
            wc[k * 40 + 20 + j] = b;
        }
        for (int j = t; j < Dh; j += blockDim.x) {
            float c0 = 0.f;
            for (int d = 0; d < Dh; ++d) c0 += (bl[d] + bs[d]) * Wn[d * Dh + j];
            cc[j] = c0 + bn[j];
        }
    } else {
        for (int idx = t; idx < Dh * Dout; idx += blockDim.x) {
            int k = idx / Dout, j = idx % Dout;
            float a = 0.f, b = 0.f;
            for (int d = 0; d < Dh; ++d) {
                float wn = Wn5[d * Dout + j];
                a += Wl5[k * Dh + d] * wn;
                b += (Wr5[k * Dh + d] + Ws5[k * Dh + d]) * wn;
            }
            wc5[k * 32 + j] = a;
            wc5[k * 32 + 16 + j] = b;
        }
        for (int j = t; j < Dout; j += blockDim.x) {
            float c0 = 0.f;
            for (int d = 0; d < Dh; ++d) c0 += (bl5[d] + bs5[d]) * Wn5[d * Dout + j];
            c5[j] = c0 + bn5[j];
        }
    }
}

// ---------------- CSR build ----------------
__global__ void count_deg(const int* __restrict__ dst, unsigned* __restrict__ cnt, int E) {
    int e = blockIdx.x * blockDim.x + threadIdx.x;
    if (e < E) atomicAdd(&cnt[dst[e]], 1u);
}

__global__ void scan_blocksums(const unsigned* __restrict__ cnt, unsigned* __restrict__ bsum, int n) {
    __shared__ unsigned sd[256];
    int b = blockIdx.x, t = threadIdx.x;
    int base = b * 1024;
    unsigned s = 0;
    for (int i = t; i < 1024; i += 256) {
        int idx = base + i;
        if (idx < n) s += cnt[idx];
    }
    sd[t] = s;
    __syncthreads();
    for (int off = 128; off > 0; off >>= 1) {
        if (t < off) sd[t] += sd[t + off];
        __syncthreads();
    }
    if (t == 0) bsum[b] = sd[0];
}

__global__ void scan_bsum(unsigned* __restrict__ bsum, int nb) {
    __shared__ unsigned sh[128];
    int t = threadIdx.x;
    unsigned v = (t < nb) ? bsum[t] : 0u;
    sh[t] = v;
    __syncthreads();
    for (int off = 1; off < 128; off <<= 1) {
        unsigned add = (t >= off) ? sh[t - off] : 0u;
        __syncthreads();
        sh[t] += add;
        __syncthreads();
    }
    if (t < nb) bsum[t] = sh[t] - v;  // exclusive
}

__global__ void scan_final(const unsigned* __restrict__ cnt, const unsigned* __restrict__ bsum,
                           unsigned* __restrict__ offs, unsigned* __restrict__ fill, int n) {
    __shared__ unsigned wsum[4], woff[4];
    int b = blockIdx.x, t = threadIdx.x;
    int base = b * 1024 + t * 4;
    unsigned v[4];
    unsigned s = 0;
#pragma unroll
    for (int i = 0; i < 4; ++i) {
        int idx = base + i;
        v[i] = (idx < n) ? cnt[idx] : 0u;
        s += v[i];
    }
    unsigned lane = t & 63;
    int w = t >> 6;
    unsigned val = s;
    for (int off = 1; off < 64; off <<= 1) {
        unsigned u = __shfl_up(val, off, 64);
        if (lane >= off) val += u;
    }
    if (lane == 63) wsum[w] = val;
    __syncthreads();
    if (t == 0) {
        unsigned r = 0;
        for (int i = 0; i < 4; ++i) { woff[i] = r; r += wsum[i]; }
    }
    __syncthreads();
    unsigned run = bsum[b] + woff[w] + (val - s);
#pragma unroll
    for (int i = 0; i < 4; ++i) {
        int idx = base + i;
        if (idx < n) {
            offs[idx] = run;
            fill[idx] = run;
            run += v[i];
            if (idx == n - 1) offs[n] = run;
        }
    }
}

__global__ void csr_fill(const int* __restrict__ src, const int* __restrict__ dst,
                         unsigned* __restrict__ fill, unsigned* __restrict__ csr, int E) {
    int e = blockIdx.x * blockDim.x + threadIdx.x;
    if (e < E) {
        unsigned p = atomicAdd(&fill[dst[e]], 1u);
        csr[p] = (unsigned)src[e];
    }
}

// ---------------- fused (lazy-BN+ReLU) + projection: xa = f(x)@A, xb = f(x)@B + c ----------------
template <int FINt, int FO, bool NORM>
__global__ __launch_bounds__(256) void gemm_kernel(
    const float* __restrict__ xin, const float* __restrict__ stats,
    const float* __restrict__ g, const float* __restrict__ be,
    const float* __restrict__ wc, const float* __restrict__ cvec,
    float* __restrict__ xa, float* __restrict__ xb)
{
    __shared__ float sscale[Dh], sshift[Dh];
    int t = threadIdx.x;
    if (NORM) {
        if (t < Dh) {
            float mu = stats[t] * (1.0f / Nn);
            float var = stats[32 + t] * (1.0f / Nn) - mu * mu;
            float sc = g[t] * rsqrtf(var + EPSV);
            sscale[t] = sc;
            sshift[t] = be[t] - mu * sc;
        }
        __syncthreads();
    }
    int n = blockIdx.x * blockDim.x + t;
    if (n >= Nn) return;

    float acc[2 * FO];
#pragma unroll
    for (int j = 0; j < 2 * FO; ++j) acc[j] = 0.f;

    const float4* xr = (const float4*)(xin + (size_t)n * FINt);
#pragma unroll
    for (int c = 0; c < FINt / 4; ++c) {
        float4 v = xr[c];
        float xs[4] = {v.x, v.y, v.z, v.w};
        if (NORM) {
#pragma unroll
            for (int kk = 0; kk < 4; ++kk)
                xs[kk] = fmaxf(xs[kk] * sscale[4 * c + kk] + sshift[4 * c + kk], 0.0f);
        }
#pragma unroll
        for (int kk = 0; kk < 4; ++kk) {
            float xk = xs[kk];
            const float* wr = wc + (4 * c + kk) * (2 * FO);  // uniform -> scalar loads
#pragma unroll
            for (int j = 0; j < 2 * FO; ++j) acc[j] = fmaf(xk, wr[j], acc[j]);
        }
    }

    float4* xao = (float4*)(xa + (size_t)n * FO);
    float4* xbo = (float4*)(xb + (size_t)n * FO);
#pragma unroll
    for (int c = 0; c < FO / 4; ++c) {
        float4 o;
        o.x = acc[4 * c + 0]; o.y = acc[4 * c + 1]; o.z = acc[4 * c + 2]; o.w = acc[4 * c + 3];
        xao[c] = o;
        float4 p;
        p.x = acc[FO + 4 * c + 0] + cvec[4 * c + 0];
        p.y = acc[FO + 4 * c + 1] + cvec[4 * c + 1];
        p.z = acc[FO + 4 * c + 2] + cvec[4 * c + 2];
        p.w = acc[FO + 4 * c + 3] + cvec[4 * c + 3];
        xbo[c] = p;
    }
}

// ---------------- pull aggregation + combine (+ BN stats) ----------------
template <int F, bool WITH_STATS>
__global__ __launch_bounds__(256) void pull_kernel(
    const unsigned* __restrict__ offs, const unsigned* __restrict__ csr,
    const float* __restrict__ xa, const float* __restrict__ xb,
    float* __restrict__ out, float* __restrict__ stats)
{
    int n = blockIdx.x * blockDim.x + threadIdx.x;
    bool act = (n < Nn);
    float h[F];
    if (act) {
        unsigned b = offs[n], e = offs[n + 1];
        float acc[F];
#pragma unroll
        for (int j = 0; j < F; ++j) acc[j] = 0.f;
        for (unsigned k = b; k < e; ++k) {
            unsigned s = csr[k];
            const float4* r = (const float4*)(xa + (size_t)s * F);
#pragma unroll
            for (int c = 0; c < F / 4; ++c) {
                float4 v = r[c];
                acc[4 * c + 0] += v.x;
                acc[4 * c + 1] += v.y;
                acc[4 * c + 2] += v.z;
                acc[4 * c + 3] += v.w;
            }
        }
        float inv = 1.0f / fmaxf((float)(e - b), 1.0f);
        const float4* xbr = (const float4*)(xb + (size_t)n * F);
#pragma unroll
        for (int c = 0; c < F / 4; ++c) {
            float4 v = xbr[c];
            h[4 * c + 0] = fmaf(acc[4 * c + 0], inv, v.x);
            h[4 * c + 1] = fmaf(acc[4 * c + 1], inv, v.y);
            h[4 * c + 2] = fmaf(acc[4 * c + 2], inv, v.z);
            h[4 * c + 3] = fmaf(acc[4 * c + 3], inv, v.w);
        }
        float4* o = (float4*)(out + (size_t)n * F);
#pragma unroll
        for (int c = 0; c < F / 4; ++c) {
            float4 v;
            v.x = h[4 * c + 0]; v.y = h[4 * c + 1]; v.z = h[4 * c + 2]; v.w = h[4 * c + 3];
            o[c] = v;
        }
    } else {
#pragma unroll
        for (int j = 0; j < F; ++j) h[j] = 0.f;
    }
    if (WITH_STATS) {
#pragma unroll
        for (int j = 0; j < F; ++j) {
            float s1 = act ? h[j] : 0.f;
            float s2 = s1 * s1;
#pragma unroll
            for (int m = 32; m > 0; m >>= 1) {
                s1 += __shfl_xor(s1, m, 64);
                s2 += __shfl_xor(s2, m, 64);
            }
            if ((threadIdx.x & 63) == 0) {
                atomicAdd(&stats[j], s1);
                atomicAdd(&stats[32 + j], s2);
            }
        }
    }
}

// ---------------- launch ----------------
extern "C" void kernel_launch(void* const* d_in, const int* in_sizes, int n_in,
                              void* d_out, int out_size, void* d_ws, size_t ws_size,
                              hipStream_t stream) {
    const float* x   = (const float*)d_in[0];
    const int* ei    = (const int*)d_in[1];
    const int* esrc  = ei;
    const int* edst  = ei + Ne;
    const float* Wl1 = (const float*)d_in[3];
    const float* bl1 = (const float*)d_in[4];
    const float* Wr1 = (const float*)d_in[5];
    const float* Ws1 = (const float*)d_in[6];
    const float* bs1 = (const float*)d_in[7];
    const float* Wn1 = (const float*)d_in[8];
    const float* bn1 = (const float*)d_in[9];
    const float* g1  = (const float*)d_in[10];
    const float* be1 = (const float*)d_in[11];
    const float* Wlm = (const float*)d_in[12];
    const float* blm = (const float*)d_in[13];
    const float* Wrm = (const float*)d_in[14];
    const float* Wsm = (const float*)d_in[15];
    const float* bsm = (const float*)d_in[16];
    const float* Wnm = (const float*)d_in[17];
    const float* bnm = (const float*)d_in[18];
    const float* gm  = (const float*)d_in[19];
    const float* bem = (const float*)d_in[20];
    const float* Wl5 = (const float*)d_in[21];
    const float* bl5 = (const float*)d_in[22];
    const float* Wr5 = (const float*)d_in[23];
    const float* Ws5 = (const float*)d_in[24];
    const float* bs5 = (const float*)d_in[25];
    const float* Wn5 = (const float*)d_in[26];
    const float* bn5 = (const float*)d_in[27];

    float* ws   = (float*)d_ws;
    unsigned* u = (unsigned*)d_ws;
    float* wc1   = ws + OFF_WC1;
    float* c1    = ws + OFF_C1;
    float* wcm   = ws + OFF_WCM;
    float* cm    = ws + OFF_CM;
    float* wc5   = ws + OFF_WC5;
    float* c5    = ws + OFF_C5;
    float* stats = ws + OFF_ST;
    unsigned* offs = u + OFF_OFFS;
    unsigned* fill = u + OFF_FILL;
    unsigned* bsum = u + OFF_BSUM;
    unsigned* cnt  = u + OFF_CNT;
    unsigned* csr  = u + OFF_CSR;
    float* xa = ws + OFF_XA;
    float* xb = ws + OFF_XB;
    float* hp = ws + OFF_HP;
    float* out = (float*)d_out;

    hipMemsetAsync(cnt, 0, Nn * sizeof(unsigned), stream);
    hipMemsetAsync(stats, 0, 256 * sizeof(float), stream);

    prep_weights<<<5, 256, 0, stream>>>(Wl1, bl1, Wr1, Ws1, bs1, Wn1, bn1,
                                        Wlm, blm, Wrm, Wsm, bsm, Wnm, bnm,
                                        Wl5, bl5, Wr5, Ws5, bs5, Wn5, bn5,
                                        wc1, c1, wcm, cm, wc5, c5);

    int eblk = (Ne + 255) / 256;
    count_deg<<<eblk, 256, 0, stream>>>(edst, cnt, Ne);
    constexpr int NB = (Nn + 1023) / 1024;  // 98
    scan_blocksums<<<NB, 256, 0, stream>>>(cnt, bsum, Nn);
    scan_bsum<<<1, 128, 0, stream>>>(bsum, NB);
    scan_final<<<NB, 256, 0, stream>>>(cnt, bsum, offs, fill, Nn);
    csr_fill<<<eblk, 256, 0, stream>>>(esrc, edst, fill, csr, Ne);

    int nblk = (Nn + 255) / 256;  // 391
    // layer 1
    gemm_kernel<FINN, Dh, false><<<nblk, 256, 0, stream>>>(x, nullptr, nullptr, nullptr, wc1, c1, xa, xb);
    pull_kernel<Dh, true><<<nblk, 256, 0, stream>>>(offs, csr, xa, xb, hp, stats + 0);
    // layer 2
    gemm_kernel<Dh, Dh, true><<<nblk, 256, 0, stream>>>(hp, stats + 0, g1, be1, wcm + 0, cm + 0, xa, xb);
    pull_kernel<Dh, true><<<nblk, 256, 0, stream>>>(offs, csr, xa, xb, hp, stats + 64);
    // layer 3
    gemm_kernel<Dh, Dh, true><<<nblk, 256, 0, stream>>>(hp, stats + 64, gm + 0, bem + 0, wcm + 800, cm + 32, xa, xb);
    pull_kernel<Dh, true><<<nblk, 256, 0, stream>>>(offs, csr, xa, xb, hp, stats + 128);
    // layer 4
    gemm_kernel<Dh, Dh, true><<<nblk, 256, 0, stream>>>(hp, stats + 128, gm + 20, bem + 20, wcm + 1600, cm + 64, xa, xb);
    pull_kernel<Dh, true><<<nblk, 256, 0, stream>>>(offs, csr, xa, xb, hp, stats + 192);
    // layer 5 (no BN/ReLU at output; lazy-norm of layer-4 applied here)
    gemm_kernel<Dh, Dout, true><<<nblk, 256, 0, stream>>>(hp, stats + 192, gm + 40, bem + 40, wc5, c5, xa, xb);
    pull_kernel<Dout, false><<<nblk, 256, 0, stream>>>(offs, csr, xa, xb, out, nullptr);
}

// Round 2
// 628.071 us; speedup vs baseline: 3.1682x; 3.1682x over previous
//
#include <hip/hip_runtime.h>

// ---------------- problem constants ----------------
constexpr int Nn   = 100000;
constexpr int Ne   = 1600000;
constexpr int FINN = 64;
constexpr int Dh   = 20;
constexpr int Dout = 16;
constexpr float EPSV = 1e-5f;

// ---------------- workspace layout (float units) ----------------
constexpr size_t OFF_WC1  = 0;         // 64*40 combined [A|B] layer1
constexpr size_t OFF_C1   = 2560;      // 32
constexpr size_t OFF_WCM  = 2592;      // 3 * 800 (20*40 each)
constexpr size_t OFF_CM   = 4992;      // 3 * 32
constexpr size_t OFF_WC5  = 5088;      // 20*32
constexpr size_t OFF_C5   = 5728;      // 32
constexpr size_t OFF_ST   = 5760;      // 4 layers * 64 (sum@+0, sumsq@+32)
constexpr size_t OFF_OFFS = 8192;      // u32, N+1 (padded 100352)
constexpr size_t OFF_FILL = 108544;    // u32, N   (padded 100352)
constexpr size_t OFF_BSUM = 208896;    // u32, 512
constexpr size_t OFF_CNT  = 209408;    // u32, N (padded 100352)
constexpr size_t OFF_CSR  = 309760;    // u32, Ne  -> ends 1,909,760
constexpr size_t OFF_XA   = 1910784;   // f32, N*20
constexpr size_t OFF_XB   = 3910784;   // f32, N*20
constexpr size_t OFF_HP   = 5910784;   // f32, N*20 -> ends 7,910,784 (~30.2 MiB)

// ---------------- weight folding ----------------
// A = Wl@Wn, B = (Wr+Ws)@Wn, c = (bl+bs)@Wn + bn   (per layer)
__global__ void prep_weights(
    const float* __restrict__ Wl1, const float* __restrict__ bl1,
    const float* __restrict__ Wr1, const float* __restrict__ Ws1,
    const float* __restrict__ bs1, const float* __restrict__ Wn1,
    const float* __restrict__ bn1,
    const float* __restrict__ Wlm, const float* __restrict__ blm,
    const float* __restrict__ Wrm, const float* __restrict__ Wsm,
    const float* __restrict__ bsm, const float* __restrict__ Wnm,
    const float* __restrict__ bnm,
    const float* __restrict__ Wl5, const float* __restrict__ bl5,
    const float* __restrict__ Wr5, const float* __restrict__ Ws5,
    const float* __restrict__ bs5, const float* __restrict__ Wn5,
    const float* __restrict__ bn5,
    float* __restrict__ wc1, float* __restrict__ c1,
    float* __restrict__ wcm, float* __restrict__ cm,
    float* __restrict__ wc5, float* __restrict__ c5)
{
    int layer = blockIdx.x;
    int t = threadIdx.x;
    if (layer == 0) {
        for (int idx = t; idx < FINN * Dh; idx += blockDim.x) {
            int k = idx / Dh, j = idx % Dh;
            float a = 0.f, b = 0.f;
            for (int d = 0; d < Dh; ++d) {
                float wn = Wn1[d * Dh + j];
                a += Wl1[k * Dh + d] * wn;
                b += (Wr1[k * Dh + d] + Ws1[k * Dh + d]) * wn;
            }
            wc1[k * 40 + j] = a;
            wc1[k * 40 + 20 + j] = b;
        }
        for (int j = t; j < Dh; j += blockDim.x) {
            float c0 = 0.f;
            for (int d = 0; d < Dh; ++d) c0 += (bl1[d] + bs1[d]) * Wn1[d * Dh + j];
            c1[j] = c0 + bn1[j];
        }
    } else if (layer <= 3) {
        int i = layer - 1;
        const float* Wl = Wlm + i * Dh * Dh;
        const float* Wr = Wrm + i * Dh * Dh;
        const float* Ws = Wsm + i * Dh * Dh;
        const float* Wn = Wnm + i * Dh * Dh;
        const float* bl = blm + i * Dh;
        const float* bs = bsm + i * Dh;
        const float* bn = bnm + i * Dh;
        float* wc = wcm + i * 800;
        float* cc = cm + i * 32;
        for (int idx = t; idx < Dh * Dh; idx += blockDim.x) {
            int k = idx / Dh, j = idx % Dh;
            float a = 0.f, b = 0.f;
            for (int d = 0; d < Dh; ++d) {
                float wn = Wn[d * Dh + j];
                a += Wl[k * Dh + d] * wn;
                b += (Wr[k * Dh + d] + Ws[k * Dh + d]) * wn;
            }
            wc[k * 40 + j] = a;
            wc[k * 40 + 20 + j] = b;
        }
        for (int j = t; j < Dh; j += blockDim.x) {
            float c0 = 0.f;
            for (int d = 0; d < Dh; ++d) c0 += (bl[d] + bs[d]) * Wn[d * Dh + j];
            cc[j] = c0 + bn[j];
        }
    } else {
        for (int idx = t; idx < Dh * Dout; idx += blockDim.x) {
            int k = idx / Dout, j = idx % Dout;
            float a = 0.f, b = 0.f;
            for (int d = 0; d < Dh; ++d) {
                float wn = Wn5[d * Dout + j];
                a += Wl5[k * Dh + d] * wn;
                b += (Wr5[k * Dh + d] + Ws5[k * Dh + d]) * wn;
            }
            wc5[k * 32 + j] = a;
            wc5[k * 32 + 16 + j] = b;
        }
        for (int j = t; j < Dout; j += blockDim.x) {
            float c0 = 0.f;
            for (int d = 0; d < Dh; ++d) c0 += (bl5[d] + bs5[d]) * Wn5[d * Dout + j];
            c5[j] = c0 + bn5[j];
        }
    }
}

// ---------------- CSR build ----------------
__global__ void count_deg(const int* __restrict__ dst, unsigned* __restrict__ cnt, int E) {
    int e = blockIdx.x * blockDim.x + threadIdx.x;
    if (e < E) atomicAdd(&cnt[dst[e]], 1u);
}

__global__ void scan_blocksums(const unsigned* __restrict__ cnt, unsigned* __restrict__ bsum, int n) {
    __shared__ unsigned sd[256];
    int b = blockIdx.x, t = threadIdx.x;
    int base = b * 1024;
    unsigned s = 0;
    for (int i = t; i < 1024; i += 256) {
        int idx = base + i;
        if (idx < n) s += cnt[idx];
    }
    sd[t] = s;
    __syncthreads();
    for (int off = 128; off > 0; off >>= 1) {
        if (t < off) sd[t] += sd[t + off];
        __syncthreads();
    }
    if (t == 0) bsum[b] = sd[0];
}

__global__ void scan_bsum(unsigned* __restrict__ bsum, int nb) {
    __shared__ unsigned sh[128];
    int t = threadIdx.x;
    unsigned v = (t < nb) ? bsum[t] : 0u;
    sh[t] = v;
    __syncthreads();
    for (int off = 1; off < 128; off <<= 1) {
        unsigned add = (t >= off) ? sh[t - off] : 0u;
        __syncthreads();
        sh[t] += add;
        __syncthreads();
    }
    if (t < nb) bsum[t] = sh[t] - v;  // exclusive
}

__global__ void scan_final(const unsigned* __restrict__ cnt, const unsigned* __restrict__ bsum,
                           unsigned* __restrict__ offs, unsigned* __restrict__ fill, int n) {
    __shared__ unsigned wsum[4], woff[4];
    int b = blockIdx.x, t = threadIdx.x;
    int base = b * 1024 + t * 4;
    unsigned v[4];
    unsigned s = 0;
#pragma unroll
    for (int i = 0; i < 4; ++i) {
        int idx = base + i;
        v[i] = (idx < n) ? cnt[idx] : 0u;
        s += v[i];
    }
    unsigned lane = t & 63;
    int w = t >> 6;
    unsigned val = s;
    for (int off = 1; off < 64; off <<= 1) {
        unsigned u = __shfl_up(val, off, 64);
        if (lane >= off) val += u;
    }
    if (lane == 63) wsum[w] = val;
    __syncthreads();
    if (t == 0) {
        unsigned r = 0;
        for (int i = 0; i < 4; ++i) { woff[i] = r; r += wsum[i]; }
    }
    __syncthreads();
    unsigned run = bsum[b] + woff[w] + (val - s);
#pragma unroll
    for (int i = 0; i < 4; ++i) {
        int idx = base + i;
        if (idx < n) {
            offs[idx] = run;
            fill[idx] = run;
            run += v[i];
            if (idx == n - 1) offs[n] = run;
        }
    }
}

__global__ void csr_fill(const int* __restrict__ src, const int* __restrict__ dst,
                         unsigned* __restrict__ fill, unsigned* __restrict__ csr, int E) {
    int e = blockIdx.x * blockDim.x + threadIdx.x;
    if (e < E) {
        unsigned p = atomicAdd(&fill[dst[e]], 1u);
        csr[p] = (unsigned)src[e];
    }
}

// ---------------- fused (lazy-BN+ReLU) + projection: xa = f(x)@A, xb = f(x)@B + c ----------------
template <int FINt, int FO, bool NORM>
__global__ __launch_bounds__(256) void gemm_kernel(
    const float* __restrict__ xin, const float* __restrict__ stats,
    const float* __restrict__ g, const float* __restrict__ be,
    const float* __restrict__ wc, const float* __restrict__ cvec,
    float* __restrict__ xa, float* __restrict__ xb)
{
    __shared__ float sscale[Dh], sshift[Dh];
    int t = threadIdx.x;
    if (NORM) {
        if (t < Dh) {
            float mu = stats[t] * (1.0f / Nn);
            float var = stats[32 + t] * (1.0f / Nn) - mu * mu;
            float sc = g[t] * rsqrtf(var + EPSV);
            sscale[t] = sc;
            sshift[t] = be[t] - mu * sc;
        }
        __syncthreads();
    }
    int n = blockIdx.x * blockDim.x + t;
    if (n >= Nn) return;

    float acc[2 * FO];
#pragma unroll
    for (int j = 0; j < 2 * FO; ++j) acc[j] = 0.f;

    const float4* xr = (const float4*)(xin + (size_t)n * FINt);
#pragma unroll
    for (int c = 0; c < FINt / 4; ++c) {
        float4 v = xr[c];
        float xs[4] = {v.x, v.y, v.z, v.w};
        if (NORM) {
#pragma unroll
            for (int kk = 0; kk < 4; ++kk)
                xs[kk] = fmaxf(xs[kk] * sscale[4 * c + kk] + sshift[4 * c + kk], 0.0f);
        }
#pragma unroll
        for (int kk = 0; kk < 4; ++kk) {
            float xk = xs[kk];
            const float* wr = wc + (4 * c + kk) * (2 * FO);  // uniform -> scalar loads
#pragma unroll
            for (int j = 0; j < 2 * FO; ++j) acc[j] = fmaf(xk, wr[j], acc[j]);
        }
    }

    float4* xao = (float4*)(xa + (size_t)n * FO);
    float4* xbo = (float4*)(xb + (size_t)n * FO);
#pragma unroll
    for (int c = 0; c < FO / 4; ++c) {
        float4 o;
        o.x = acc[4 * c + 0]; o.y = acc[4 * c + 1]; o.z = acc[4 * c + 2]; o.w = acc[4 * c + 3];
        xao[c] = o;
        float4 p;
        p.x = acc[FO + 4 * c + 0] + cvec[4 * c + 0];
        p.y = acc[FO + 4 * c + 1] + cvec[4 * c + 1];
        p.z = acc[FO + 4 * c + 2] + cvec[4 * c + 2];
        p.w = acc[FO + 4 * c + 3] + cvec[4 * c + 3];
        xbo[c] = p;
    }
}

// ---------------- pull aggregation + combine (+ BN stats) ----------------
// One thread per (node, float4 chunk): C = F/4 threads per node.
// 8-deep batched csr reads + independent gathers for memory-level parallelism.
template <int F, bool WITH_STATS>
__global__ __launch_bounds__(256) void pull_kernel(
    const unsigned* __restrict__ offs, const unsigned* __restrict__ csr,
    const float* __restrict__ xa, const float* __restrict__ xb,
    float* __restrict__ out, float* __restrict__ stats)
{
    constexpr int C = F / 4;
    __shared__ float sstat[2 * F];
    int t = threadIdx.x;
    if (WITH_STATS) {
        if (t < 2 * F) sstat[t] = 0.f;
        __syncthreads();
    }
    int tid = blockIdx.x * blockDim.x + t;
    int n = tid / C;
    int c = tid % C;
    bool act = (n < Nn);
    float4 h = {0.f, 0.f, 0.f, 0.f};
    if (act) {
        unsigned b = offs[n], e = offs[n + 1];
        const float* base = xa + (size_t)c * 4;
        float4 acc = {0.f, 0.f, 0.f, 0.f};
        unsigned k = b;
        for (; k + 8 <= e; k += 8) {
            unsigned s[8];
#pragma unroll
            for (int i = 0; i < 8; ++i) s[i] = csr[k + i];
            float4 v[8];
#pragma unroll
            for (int i = 0; i < 8; ++i) v[i] = *(const float4*)(base + (size_t)s[i] * F);
#pragma unroll
            for (int i = 0; i < 8; ++i) {
                acc.x += v[i].x; acc.y += v[i].y; acc.z += v[i].z; acc.w += v[i].w;
            }
        }
        for (; k < e; ++k) {
            unsigned s0 = csr[k];
            float4 v = *(const float4*)(base + (size_t)s0 * F);
            acc.x += v.x; acc.y += v.y; acc.z += v.z; acc.w += v.w;
        }
        float inv = 1.0f / fmaxf((float)(e - b), 1.0f);
        float4 xv = *(const float4*)(xb + (size_t)n * F + c * 4);
        h.x = fmaf(acc.x, inv, xv.x);
        h.y = fmaf(acc.y, inv, xv.y);
        h.z = fmaf(acc.z, inv, xv.z);
        h.w = fmaf(acc.w, inv, xv.w);
        *(float4*)(out + (size_t)n * F + c * 4) = h;
    }
    if (WITH_STATS) {
        if (act) {
            atomicAdd(&sstat[c * 4 + 0], h.x);
            atomicAdd(&sstat[c * 4 + 1], h.y);
            atomicAdd(&sstat[c * 4 + 2], h.z);
            atomicAdd(&sstat[c * 4 + 3], h.w);
            atomicAdd(&sstat[F + c * 4 + 0], h.x * h.x);
            atomicAdd(&sstat[F + c * 4 + 1], h.y * h.y);
            atomicAdd(&sstat[F + c * 4 + 2], h.z * h.z);
            atomicAdd(&sstat[F + c * 4 + 3], h.w * h.w);
        }
        __syncthreads();
        if (t < F) {
            atomicAdd(&stats[t], sstat[t]);
        } else if (t < 2 * F) {
            atomicAdd(&stats[32 + (t - F)], sstat[t]);
        }
    }
}

// ---------------- launch ----------------
extern "C" void kernel_launch(void* const* d_in, const int* in_sizes, int n_in,
                              void* d_out, int out_size, void* d_ws, size_t ws_size,
                              hipStream_t stream) {
    const float* x   = (const float*)d_in[0];
    const int* ei    = (const int*)d_in[1];
    const int* esrc  = ei;
    const int* edst  = ei + Ne;
    const float* Wl1 = (const float*)d_in[3];
    const float* bl1 = (const float*)d_in[4];
    const float* Wr1 = (const float*)d_in[5];
    const float* Ws1 = (const float*)d_in[6];
    const float* bs1 = (const float*)d_in[7];
    const float* Wn1 = (const float*)d_in[8];
    const float* bn1 = (const float*)d_in[9];
    const float* g1  = (const float*)d_in[10];
    const float* be1 = (const float*)d_in[11];
    const float* Wlm = (const float*)d_in[12];
    const float* blm = (const float*)d_in[13];
    const float* Wrm = (const float*)d_in[14];
    const float* Wsm = (const float*)d_in[15];
    const float* bsm = (const float*)d_in[16];
    const float* Wnm = (const float*)d_in[17];
    const float* bnm = (const float*)d_in[18];
    const float* gm  = (const float*)d_in[19];
    const float* bem = (const float*)d_in[20];
    const float* Wl5 = (const float*)d_in[21];
    const float* bl5 = (const float*)d_in[22];
    const float* Wr5 = (const float*)d_in[23];
    const float* Ws5 = (const float*)d_in[24];
    const float* bs5 = (const float*)d_in[25];
    const float* Wn5 = (const float*)d_in[26];
    const float* bn5 = (const float*)d_in[27];

    float* ws   = (float*)d_ws;
    unsigned* u = (unsigned*)d_ws;
    float* wc1   = ws + OFF_WC1;
    float* c1    = ws + OFF_C1;
    float* wcm   = ws + OFF_WCM;
    float* cm    = ws + OFF_CM;
    float* wc5   = ws + OFF_WC5;
    float* c5    = ws + OFF_C5;
    float* stats = ws + OFF_ST;
    unsigned* offs = u + OFF_OFFS;
    unsigned* fill = u + OFF_FILL;
    unsigned* bsum = u + OFF_BSUM;
    unsigned* cnt  = u + OFF_CNT;
    unsigned* csr  = u + OFF_CSR;
    float* xa = ws + OFF_XA;
    float* xb = ws + OFF_XB;
    float* hp = ws + OFF_HP;
    float* out = (float*)d_out;

    hipMemsetAsync(cnt, 0, Nn * sizeof(unsigned), stream);
    hipMemsetAsync(stats, 0, 256 * sizeof(float), stream);

    prep_weights<<<5, 256, 0, stream>>>(Wl1, bl1, Wr1, Ws1, bs1, Wn1, bn1,
                                        Wlm, blm, Wrm, Wsm, bsm, Wnm, bnm,
                                        Wl5, bl5, Wr5, Ws5, bs5, Wn5, bn5,
                                        wc1, c1, wcm, cm, wc5, c5);

    int eblk = (Ne + 255) / 256;
    count_deg<<<eblk, 256, 0, stream>>>(edst, cnt, Ne);
    constexpr int NB = (Nn + 1023) / 1024;  // 98
    scan_blocksums<<<NB, 256, 0, stream>>>(cnt, bsum, Nn);
    scan_bsum<<<1, 128, 0, stream>>>(bsum, NB);
    scan_final<<<NB, 256, 0, stream>>>(cnt, bsum, offs, fill, Nn);
    csr_fill<<<eblk, 256, 0, stream>>>(esrc, edst, fill, csr, Ne);

    int nblk = (Nn + 255) / 256;                  // 391  (gemm: node per thread)
    int pblk20 = (Nn * 5 + 255) / 256;            // 1954 (pull F=20: 5 thr/node)
    int pblk16 = (Nn * 4 + 255) / 256;            // 1563 (pull F=16: 4 thr/node)

    // layer 1
    gemm_kernel<FINN, Dh, false><<<nblk, 256, 0, stream>>>(x, nullptr, nullptr, nullptr, wc1, c1, xa, xb);
    pull_kernel<Dh, true><<<pblk20, 256, 0, stream>>>(offs, csr, xa, xb, hp, stats + 0);
    // layer 2
    gemm_kernel<Dh, Dh, true><<<nblk, 256, 0, stream>>>(hp, stats + 0, g1, be1, wcm + 0, cm + 0, xa, xb);
    pull_kernel<Dh, true><<<pblk20, 256, 0, stream>>>(offs, csr, xa, xb, hp, stats + 64);
    // layer 3
    gemm_kernel<Dh, Dh, true><<<nblk, 256, 0, stream>>>(hp, stats + 64, gm + 0, bem + 0, wcm + 800, cm + 32, xa, xb);
    pull_kernel<Dh, true><<<pblk20, 256, 0, stream>>>(offs, csr, xa, xb, hp, stats + 128);
    // layer 4
    gemm_kernel<Dh, Dh, true><<<nblk, 256, 0, stream>>>(hp, stats + 128, gm + 20, bem + 20, wcm + 1600, cm + 64, xa, xb);
    pull_kernel<Dh, true><<<pblk20, 256, 0, stream>>>(offs, csr, xa, xb, hp, stats + 192);
    // layer 5 (no BN/ReLU at output; lazy-norm of layer-4 applied here)
    gemm_kernel<Dh, Dout, true><<<nblk, 256, 0, stream>>>(hp, stats + 192, gm + 40, bem + 40, wc5, c5, xa, xb);
    pull_kernel<Dout, false><<<pblk16, 256, 0, stream>>>(offs, csr, xa, xb, out, nullptr);
}

// Round 3
// 606.834 us; speedup vs baseline: 3.2791x; 1.0350x over previous
//
#include <hip/hip_runtime.h>

// ---------------- problem constants ----------------
constexpr int Nn   = 100000;
constexpr int Ne   = 1600000;
constexpr int FINN = 64;
constexpr int Dh   = 20;
constexpr int Dout = 16;
constexpr float EPSV = 1e-5f;

// ---------------- workspace layout (float units) ----------------
constexpr size_t OFF_WC1  = 0;         // 64*40 combined [A|B] layer1
constexpr size_t OFF_C1   = 2560;      // 32
constexpr size_t OFF_WCM  = 2592;      // 3 * 800 (20*40 each)
constexpr size_t OFF_CM   = 4992;      // 3 * 32
constexpr size_t OFF_WC5  = 5088;      // 20*32
constexpr size_t OFF_C5   = 5728;      // 32
constexpr size_t OFF_ST   = 5760;      // 4 layers * 64 (sum@+0, sumsq@+32)
constexpr size_t OFF_OFFS = 8192;      // u32, N+1 (padded 100352)
constexpr size_t OFF_FILL = 108544;    // u32, N   (padded 100352)
constexpr size_t OFF_BSUM = 208896;    // u32, 512
constexpr size_t OFF_CNT  = 209408;    // u32, N (padded 100352)
constexpr size_t OFF_CSR  = 309760;    // u32, Ne  -> ends 1,909,760
constexpr size_t OFF_XA   = 1910784;   // bf16 (u16), N*20 -> 1M floats
constexpr size_t OFF_XB   = 3910784;   // f32, N*20
constexpr size_t OFF_HP   = 5910784;   // f32, N*20 -> ends 7,910,784 (~30.2 MiB)

// bf16 <-> f32 (bit-exact expand; RNE pack). Avoids header-version issues.
__device__ inline unsigned short f2b(float x) {
    unsigned b = __float_as_uint(x);
    return (unsigned short)((b + 0x7FFFu + ((b >> 16) & 1u)) >> 16);
}
__device__ inline float b2f(unsigned short u) {
    return __uint_as_float(((unsigned)u) << 16);
}

// ---------------- weight folding ----------------
// A = Wl@Wn, B = (Wr+Ws)@Wn, c = (bl+bs)@Wn + bn   (per layer)
__global__ void prep_weights(
    const float* __restrict__ Wl1, const float* __restrict__ bl1,
    const float* __restrict__ Wr1, const float* __restrict__ Ws1,
    const float* __restrict__ bs1, const float* __restrict__ Wn1,
    const float* __restrict__ bn1,
    const float* __restrict__ Wlm, const float* __restrict__ blm,
    const float* __restrict__ Wrm, const float* __restrict__ Wsm,
    const float* __restrict__ bsm, const float* __restrict__ Wnm,
    const float* __restrict__ bnm,
    const float* __restrict__ Wl5, const float* __restrict__ bl5,
    const float* __restrict__ Wr5, const float* __restrict__ Ws5,
    const float* __restrict__ bs5, const float* __restrict__ Wn5,
    const float* __restrict__ bn5,
    float* __restrict__ wc1, float* __restrict__ c1,
    float* __restrict__ wcm, float* __restrict__ cm,
    float* __restrict__ wc5, float* __restrict__ c5)
{
    int layer = blockIdx.x;
    int t = threadIdx.x;
    if (layer == 0) {
        for (int idx = t; idx < FINN * Dh; idx += blockDim.x) {
            int k = idx / Dh, j = idx % Dh;
            float a = 0.f, b = 0.f;
            for (int d = 0; d < Dh; ++d) {
                float wn = Wn1[d * Dh + j];
                a += Wl1[k * Dh + d] * wn;
                b += (Wr1[k * Dh + d] + Ws1[k * Dh + d]) * wn;
            }
            wc1[k * 40 + j] = a;
            wc1[k * 40 + 20 + j] = b;
        }
        for (int j = t; j < Dh; j += blockDim.x) {
            float c0 = 0.f;
            for (int d = 0; d < Dh; ++d) c0 += (bl1[d] + bs1[d]) * Wn1[d * Dh + j];
            c1[j] = c0 + bn1[j];
        }
    } else if (layer <= 3) {
        int i = layer - 1;
        const float* Wl = Wlm + i * Dh * Dh;
        const float* Wr = Wrm + i * Dh * Dh;
        const float* Ws = Wsm + i * Dh * Dh;
        const float* Wn = Wnm + i * Dh * Dh;
        const float* bl = blm + i * Dh;
        const float* bs = bsm + i * Dh;
        const float* bn = bnm + i * Dh;
        float* wc = wcm + i * 800;
        float* cc = cm + i * 32;
        for (int idx = t; idx < Dh * Dh; idx += blockDim.x) {
            int k = idx / Dh, j = idx % Dh;
            float a = 0.f, b = 0.f;
            for (int d = 0; d < Dh; ++d) {
                float wn = Wn[d * Dh + j];
                a += Wl[k * Dh + d] * wn;
                b += (Wr[k * Dh + d] + Ws[k * Dh + d]) * wn;
            }
            wc[k * 40 + j] = a;
            wc[k * 40 + 20 + j] = b;
        }
        for (int j = t; j < Dh; j += blockDim.x) {
            float c0 = 0.f;
            for (int d = 0; d < Dh; ++d) c0 += (bl[d] + bs[d]) * Wn[d * Dh + j];
            cc[j] = c0 + bn[j];
        }
    } else {
        for (int idx = t; idx < Dh * Dout; idx += blockDim.x) {
            int k = idx / Dout, j = idx % Dout;
            float a = 0.f, b = 0.f;
            for (int d = 0; d < Dh; ++d) {
                float wn = Wn5[d * Dout + j];
                a += Wl5[k * Dh + d] * wn;
                b += (Wr5[k * Dh + d] + Ws5[k * Dh + d]) * wn;
            }
            wc5[k * 32 + j] = a;
            wc5[k * 32 + 16 + j] = b;
        }
        for (int j = t; j < Dout; j += blockDim.x) {
            float c0 = 0.f;
            for (int d = 0; d < Dh; ++d) c0 += (bl5[d] + bs5[d]) * Wn5[d * Dout + j];
            c5[j] = c0 + bn5[j];
        }
    }
}

// ---------------- CSR build ----------------
__global__ void count_deg(const int* __restrict__ dst, unsigned* __restrict__ cnt, int E) {
    int e = blockIdx.x * blockDim.x + threadIdx.x;
    if (e < E) atomicAdd(&cnt[dst[e]], 1u);
}

__global__ void scan_blocksums(const unsigned* __restrict__ cnt, unsigned* __restrict__ bsum, int n) {
    __shared__ unsigned sd[256];
    int b = blockIdx.x, t = threadIdx.x;
    int base = b * 1024;
    unsigned s = 0;
    for (int i = t; i < 1024; i += 256) {
        int idx = base + i;
        if (idx < n) s += cnt[idx];
    }
    sd[t] = s;
    __syncthreads();
    for (int off = 128; off > 0; off >>= 1) {
        if (t < off) sd[t] += sd[t + off];
        __syncthreads();
    }
    if (t == 0) bsum[b] = sd[0];
}

__global__ void scan_bsum(unsigned* __restrict__ bsum, int nb) {
    __shared__ unsigned sh[128];
    int t = threadIdx.x;
    unsigned v = (t < nb) ? bsum[t] : 0u;
    sh[t] = v;
    __syncthreads();
    for (int off = 1; off < 128; off <<= 1) {
        unsigned add = (t >= off) ? sh[t - off] : 0u;
        __syncthreads();
        sh[t] += add;
        __syncthreads();
    }
    if (t < nb) bsum[t] = sh[t] - v;  // exclusive
}

__global__ void scan_final(const unsigned* __restrict__ cnt, const unsigned* __restrict__ bsum,
                           unsigned* __restrict__ offs, unsigned* __restrict__ fill, int n) {
    __shared__ unsigned wsum[4], woff[4];
    int b = blockIdx.x, t = threadIdx.x;
    int base = b * 1024 + t * 4;
    unsigned v[4];
    unsigned s = 0;
#pragma unroll
    for (int i = 0; i < 4; ++i) {
        int idx = base + i;
        v[i] = (idx < n) ? cnt[idx] : 0u;
        s += v[i];
    }
    unsigned lane = t & 63;
    int w = t >> 6;
    unsigned val = s;
    for (int off = 1; off < 64; off <<= 1) {
        unsigned u = __shfl_up(val, off, 64);
        if (lane >= off) val += u;
    }
    if (lane == 63) wsum[w] = val;
    __syncthreads();
    if (t == 0) {
        unsigned r = 0;
        for (int i = 0; i < 4; ++i) { woff[i] = r; r += wsum[i]; }
    }
    __syncthreads();
    unsigned run = bsum[b] + woff[w] + (val - s);
#pragma unroll
    for (int i = 0; i < 4; ++i) {
        int idx = base + i;
        if (idx < n) {
            offs[idx] = run;
            fill[idx] = run;
            run += v[i];
            if (idx == n - 1) offs[n] = run;
        }
    }
}

__global__ void csr_fill(const int* __restrict__ src, const int* __restrict__ dst,
                         unsigned* __restrict__ fill, unsigned* __restrict__ csr, int E) {
    int e = blockIdx.x * blockDim.x + threadIdx.x;
    if (e < E) {
        unsigned p = atomicAdd(&fill[dst[e]], 1u);
        csr[p] = (unsigned)src[e];
    }
}

// ---------------- fused (lazy-BN+ReLU) + projection: xa(bf16) = f(x)@A, xb = f(x)@B + c ------
template <int FINt, int FO, bool NORM>
__global__ __launch_bounds__(256) void gemm_kernel(
    const float* __restrict__ xin, const float* __restrict__ stats,
    const float* __restrict__ g, const float* __restrict__ be,
    const float* __restrict__ wc, const float* __restrict__ cvec,
    unsigned short* __restrict__ xa, float* __restrict__ xb)
{
    __shared__ float sscale[Dh], sshift[Dh];
    int t = threadIdx.x;
    if (NORM) {
        if (t < Dh) {
            float mu = stats[t] * (1.0f / Nn);
            float var = stats[32 + t] * (1.0f / Nn) - mu * mu;
            float sc = g[t] * rsqrtf(var + EPSV);
            sscale[t] = sc;
            sshift[t] = be[t] - mu * sc;
        }
        __syncthreads();
    }
    int n = blockIdx.x * blockDim.x + t;
    if (n >= Nn) return;

    float acc[2 * FO];
#pragma unroll
    for (int j = 0; j < 2 * FO; ++j) acc[j] = 0.f;

    const float4* xr = (const float4*)(xin + (size_t)n * FINt);
#pragma unroll
    for (int c = 0; c < FINt / 4; ++c) {
        float4 v = xr[c];
        float xs[4] = {v.x, v.y, v.z, v.w};
        if (NORM) {
#pragma unroll
            for (int kk = 0; kk < 4; ++kk)
                xs[kk] = fmaxf(xs[kk] * sscale[4 * c + kk] + sshift[4 * c + kk], 0.0f);
        }
#pragma unroll
        for (int kk = 0; kk < 4; ++kk) {
            float xk = xs[kk];
            const float* wr = wc + (4 * c + kk) * (2 * FO);  // uniform -> scalar loads
#pragma unroll
            for (int j = 0; j < 2 * FO; ++j) acc[j] = fmaf(xk, wr[j], acc[j]);
        }
    }

    ushort4* xao = (ushort4*)(xa + (size_t)n * FO);
    float4* xbo = (float4*)(xb + (size_t)n * FO);
#pragma unroll
    for (int c = 0; c < FO / 4; ++c) {
        ushort4 o;
        o.x = f2b(acc[4 * c + 0]);
        o.y = f2b(acc[4 * c + 1]);
        o.z = f2b(acc[4 * c + 2]);
        o.w = f2b(acc[4 * c + 3]);
        xao[c] = o;
        float4 p;
        p.x = acc[FO + 4 * c + 0] + cvec[4 * c + 0];
        p.y = acc[FO + 4 * c + 1] + cvec[4 * c + 1];
        p.z = acc[FO + 4 * c + 2] + cvec[4 * c + 2];
        p.w = acc[FO + 4 * c + 3] + cvec[4 * c + 3];
        xbo[c] = p;
    }
}

// ---------------- pull aggregation + combine (+ BN stats) ----------------
// One thread per (node, 4-feature chunk): C = F/4 threads per node.
// Gather table is bf16 (4MB -> L2-resident); 8-deep batched gathers for MLP.
template <int F, bool WITH_STATS>
__global__ __launch_bounds__(256) void pull_kernel(
    const unsigned* __restrict__ offs, const unsigned* __restrict__ csr,
    const unsigned short* __restrict__ xa, const float* __restrict__ xb,
    float* __restrict__ out, float* __restrict__ stats)
{
    constexpr int C = F / 4;
    __shared__ float sstat[2 * F];
    int t = threadIdx.x;
    if (WITH_STATS) {
        if (t < 2 * F) sstat[t] = 0.f;
        __syncthreads();
    }
    int tid = blockIdx.x * blockDim.x + t;
    int n = tid / C;
    int c = tid % C;
    bool act = (n < Nn);
    float4 h = {0.f, 0.f, 0.f, 0.f};
    if (act) {
        unsigned b = offs[n], e = offs[n + 1];
        const unsigned short* base = xa + (size_t)c * 4;
        float4 acc = {0.f, 0.f, 0.f, 0.f};
        unsigned k = b;
        for (; k + 8 <= e; k += 8) {
            unsigned s[8];
#pragma unroll
            for (int i = 0; i < 8; ++i) s[i] = csr[k + i];
            ushort4 v[8];
#pragma unroll
            for (int i = 0; i < 8; ++i) v[i] = *(const ushort4*)(base + (size_t)s[i] * F);
#pragma unroll
            for (int i = 0; i < 8; ++i) {
                acc.x += b2f(v[i].x); acc.y += b2f(v[i].y);
                acc.z += b2f(v[i].z); acc.w += b2f(v[i].w);
            }
        }
        for (; k < e; ++k) {
            unsigned s0 = csr[k];
            ushort4 v = *(const ushort4*)(base + (size_t)s0 * F);
            acc.x += b2f(v.x); acc.y += b2f(v.y); acc.z += b2f(v.z); acc.w += b2f(v.w);
        }
        float inv = 1.0f / fmaxf((float)(e - b), 1.0f);
        float4 xv = *(const float4*)(xb + (size_t)n * F + c * 4);
        h.x = fmaf(acc.x, inv, xv.x);
        h.y = fmaf(acc.y, inv, xv.y);
        h.z = fmaf(acc.z, inv, xv.z);
        h.w = fmaf(acc.w, inv, xv.w);
        *(float4*)(out + (size_t)n * F + c * 4) = h;
    }
    if (WITH_STATS) {
        if (act) {
            atomicAdd(&sstat[c * 4 + 0], h.x);
            atomicAdd(&sstat[c * 4 + 1], h.y);
            atomicAdd(&sstat[c * 4 + 2], h.z);
            atomicAdd(&sstat[c * 4 + 3], h.w);
            atomicAdd(&sstat[F + c * 4 + 0], h.x * h.x);
            atomicAdd(&sstat[F + c * 4 + 1], h.y * h.y);
            atomicAdd(&sstat[F + c * 4 + 2], h.z * h.z);
            atomicAdd(&sstat[F + c * 4 + 3], h.w * h.w);
        }
        __syncthreads();
        if (t < F) {
            atomicAdd(&stats[t], sstat[t]);
        } else if (t < 2 * F) {
            atomicAdd(&stats[32 + (t - F)], sstat[t]);
        }
    }
}

// ---------------- launch ----------------
extern "C" void kernel_launch(void* const* d_in, const int* in_sizes, int n_in,
                              void* d_out, int out_size, void* d_ws, size_t ws_size,
                              hipStream_t stream) {
    const float* x   = (const float*)d_in[0];
    const int* ei    = (const int*)d_in[1];
    const int* esrc  = ei;
    const int* edst  = ei + Ne;
    const float* Wl1 = (const float*)d_in[3];
    const float* bl1 = (const float*)d_in[4];
    const float* Wr1 = (const float*)d_in[5];
    const float* Ws1 = (const float*)d_in[6];
    const float* bs1 = (const float*)d_in[7];
    const float* Wn1 = (const float*)d_in[8];
    const float* bn1 = (const float*)d_in[9];
    const float* g1  = (const float*)d_in[10];
    const float* be1 = (const float*)d_in[11];
    const float* Wlm = (const float*)d_in[12];
    const float* blm = (const float*)d_in[13];
    const float* Wrm = (const float*)d_in[14];
    const float* Wsm = (const float*)d_in[15];
    const float* bsm = (const float*)d_in[16];
    const float* Wnm = (const float*)d_in[17];
    const float* bnm = (const float*)d_in[18];
    const float* gm  = (const float*)d_in[19];
    const float* bem = (const float*)d_in[20];
    const float* Wl5 = (const float*)d_in[21];
    const float* bl5 = (const float*)d_in[22];
    const float* Wr5 = (const float*)d_in[23];
    const float* Ws5 = (const float*)d_in[24];
    const float* bs5 = (const float*)d_in[25];
    const float* Wn5 = (const float*)d_in[26];
    const float* bn5 = (const float*)d_in[27];

    float* ws   = (float*)d_ws;
    unsigned* u = (unsigned*)d_ws;
    float* wc1   = ws + OFF_WC1;
    float* c1    = ws + OFF_C1;
    float* wcm   = ws + OFF_WCM;
    float* cm    = ws + OFF_CM;
    float* wc5   = ws + OFF_WC5;
    float* c5    = ws + OFF_C5;
    float* stats = ws + OFF_ST;
    unsigned* offs = u + OFF_OFFS;
    unsigned* fill = u + OFF_FILL;
    unsigned* bsum = u + OFF_BSUM;
    unsigned* cnt  = u + OFF_CNT;
    unsigned* csr  = u + OFF_CSR;
    unsigned short* xa = (unsigned short*)(ws + OFF_XA);
    float* xb = ws + OFF_XB;
    float* hp = ws + OFF_HP;
    float* out = (float*)d_out;

    hipMemsetAsync(cnt, 0, Nn * sizeof(unsigned), stream);
    hipMemsetAsync(stats, 0, 256 * sizeof(float), stream);

    prep_weights<<<5, 256, 0, stream>>>(Wl1, bl1, Wr1, Ws1, bs1, Wn1, bn1,
                                        Wlm, blm, Wrm, Wsm, bsm, Wnm, bnm,
                                        Wl5, bl5, Wr5, Ws5, bs5, Wn5, bn5,
                                        wc1, c1, wcm, cm, wc5, c5);

    int eblk = (Ne + 255) / 256;
    count_deg<<<eblk, 256, 0, stream>>>(edst, cnt, Ne);
    constexpr int NB = (Nn + 1023) / 1024;  // 98
    scan_blocksums<<<NB, 256, 0, stream>>>(cnt, bsum, Nn);
    scan_bsum<<<1, 128, 0, stream>>>(bsum, NB);
    scan_final<<<NB, 256, 0, stream>>>(cnt, bsum, offs, fill, Nn);
    csr_fill<<<eblk, 256, 0, stream>>>(esrc, edst, fill, csr, Ne);

    int nblk = (Nn + 255) / 256;                  // 391  (gemm: node per thread)
    int pblk20 = (Nn * 5 + 255) / 256;            // 1954 (pull F=20: 5 thr/node)
    int pblk16 = (Nn * 4 + 255) / 256;            // 1563 (pull F=16: 4 thr/node)

    // layer 1
    gemm_kernel<FINN, Dh, false><<<nblk, 256, 0, stream>>>(x, nullptr, nullptr, nullptr, wc1, c1, xa, xb);
    pull_kernel<Dh, true><<<pblk20, 256, 0, stream>>>(offs, csr, xa, xb, hp, stats + 0);
    // layer 2
    gemm_kernel<Dh, Dh, true><<<nblk, 256, 0, stream>>>(hp, stats + 0, g1, be1, wcm + 0, cm + 0, xa, xb);
    pull_kernel<Dh, true><<<pblk20, 256, 0, stream>>>(offs, csr, xa, xb, hp, stats + 64);
    // layer 3
    gemm_kernel<Dh, Dh, true><<<nblk, 256, 0, stream>>>(hp, stats + 64, gm + 0, bem + 0, wcm + 800, cm + 32, xa, xb);
    pull_kernel<Dh, true><<<pblk20, 256, 0, stream>>>(offs, csr, xa, xb, hp, stats + 128);
    // layer 4
    gemm_kernel<Dh, Dh, true><<<nblk, 256, 0, stream>>>(hp, stats + 128, gm + 20, bem + 20, wcm + 1600, cm + 64, xa, xb);
    pull_kernel<Dh, true><<<pblk20, 256, 0, stream>>>(offs, csr, xa, xb, hp, stats + 192);
    // layer 5 (no BN/ReLU at output; lazy-norm of layer-4 applied here)
    gemm_kernel<Dh, Dout, true><<<nblk, 256, 0, stream>>>(hp, stats + 192, gm + 40, bem + 40, wc5, c5, xa, xb);
    pull_kernel<Dout, false><<<pblk16, 256, 0, stream>>>(offs, csr, xa, xb, out, nullptr);
}

// Round 4
// 548.921 us; speedup vs baseline: 3.6251x; 1.1055x over previous
//
#include <hip/hip_runtime.h>

// ---------------- problem constants ----------------
constexpr int Nn   = 100000;
constexpr int Ne   = 1600000;
constexpr int FINN = 64;
constexpr int Dh   = 20;
constexpr int Dout = 16;
constexpr float EPSV = 1e-5f;

// CSR-build partitioning: 8 dst-ranges (XCD-locality heuristic) x 48 edge-slices
constexpr int NXCD   = 8;
constexpr int RANGE  = Nn / NXCD;            // 12500 nodes per range
constexpr int NSLICE = 48;
constexpr int SLICE_E = (Ne + NSLICE - 1) / NSLICE;  // 33334
constexpr int PSTR   = 100352;               // part stride per slice (padded Nn)

// ---------------- workspace layout (float units) ----------------
constexpr size_t OFF_WC1  = 0;         // 64*40 combined [A|B] layer1
constexpr size_t OFF_C1   = 2560;      // 32
constexpr size_t OFF_WCM  = 2592;      // 3 * 800 (20*40 each)
constexpr size_t OFF_CM   = 4992;      // 3 * 32
constexpr size_t OFF_WC5  = 5088;      // 20*32
constexpr size_t OFF_C5   = 5728;      // 32
constexpr size_t OFF_ST   = 5760;      // 4 layers * 64 (sum@+0, sumsq@+32)
constexpr size_t OFF_OFFS = 8192;      // u32, N+1 (padded 100352)
constexpr size_t OFF_BSUM = 208896;    // u32, 512
constexpr size_t OFF_CNT  = 209408;    // u32, N (padded 100352)
constexpr size_t OFF_CSR  = 309760;    // u32, Ne  -> ends 1,909,760
constexpr size_t OFF_XA   = 1910784;   // bf16 (u16), N*20 used; ALSO part[] lives here pre-gemm
constexpr size_t OFF_XB   = 3910784;   // f32, N*20
constexpr size_t OFF_HP   = 5910784;   // f32, N*20 -> ends 7,910,784 (~30.2 MiB)
// part[] (u16, NSLICE*PSTR = 9.6MB) overlaps XA+XB head: dead before gemm1 writes them.

// bf16 <-> f32 (bit-exact expand; RNE pack).
__device__ inline unsigned short f2b(float x) {
    unsigned b = __float_as_uint(x);
    return (unsigned short)((b + 0x7FFFu + ((b >> 16) & 1u)) >> 16);
}
__device__ inline float b2f(unsigned short u) {
    return __uint_as_float(((unsigned)u) << 16);
}

// ---------------- weight folding ----------------
// A = Wl@Wn, B = (Wr+Ws)@Wn, c = (bl+bs)@Wn + bn   (per layer)
__global__ void prep_weights(
    const float* __restrict__ Wl1, const float* __restrict__ bl1,
    const float* __restrict__ Wr1, const float* __restrict__ Ws1,
    const float* __restrict__ bs1, const float* __restrict__ Wn1,
    const float* __restrict__ bn1,
    const float* __restrict__ Wlm, const float* __restrict__ blm,
    const float* __restrict__ Wrm, const float* __restrict__ Wsm,
    const float* __restrict__ bsm, const float* __restrict__ Wnm,
    const float* __restrict__ bnm,
    const float* __restrict__ Wl5, const float* __restrict__ bl5,
    const float* __restrict__ Wr5, const float* __restrict__ Ws5,
    const float* __restrict__ bs5, const float* __restrict__ Wn5,
    const float* __restrict__ bn5,
    float* __restrict__ wc1, float* __restrict__ c1,
    float* __restrict__ wcm, float* __restrict__ cm,
    float* __restrict__ wc5, float* __restrict__ c5)
{
    int layer = blockIdx.x;
    int t = threadIdx.x;
    if (layer == 0) {
        for (int idx = t; idx < FINN * Dh; idx += blockDim.x) {
            int k = idx / Dh, j = idx % Dh;
            float a = 0.f, b = 0.f;
            for (int d = 0; d < Dh; ++d) {
                float wn = Wn1[d * Dh + j];
                a += Wl1[k * Dh + d] * wn;
                b += (Wr1[k * Dh + d] + Ws1[k * Dh + d]) * wn;
            }
            wc1[k * 40 + j] = a;
            wc1[k * 40 + 20 + j] = b;
        }
        for (int j = t; j < Dh; j += blockDim.x) {
            float c0 = 0.f;
            for (int d = 0; d < Dh; ++d) c0 += (bl1[d] + bs1[d]) * Wn1[d * Dh + j];
            c1[j] = c0 + bn1[j];
        }
    } else if (layer <= 3) {
        int i = layer - 1;
        const float* Wl = Wlm + i * Dh * Dh;
        const float* Wr = Wrm + i * Dh * Dh;
        const float* Ws = Wsm + i * Dh * Dh;
        const float* Wn = Wnm + i * Dh * Dh;
        const float* bl = blm + i * Dh;
        const float* bs = bsm + i * Dh;
        const float* bn = bnm + i * Dh;
        float* wc = wcm + i * 800;
        float* cc = cm + i * 32;
        for (int idx = t; idx < Dh * Dh; idx += blockDim.x) {
            int k = idx / Dh, j = idx % Dh;
            float a = 0.f, b = 0.f;
            for (int d = 0; d < Dh; ++d) {
                float wn = Wn[d * Dh + j];
                a += Wl[k * Dh + d] * wn;
                b += (Wr[k * Dh + d] + Ws[k * Dh + d]) * wn;
            }
            wc[k * 40 + j] = a;
            wc[k * 40 + 20 + j] = b;
        }
        for (int j = t; j < Dh; j += blockDim.x) {
            float c0 = 0.f;
            for (int d = 0; d < Dh; ++d) c0 += (bl[d] + bs[d]) * Wn[d * Dh + j];
            cc[j] = c0 + bn[j];
        }
    } else {
        for (int idx = t; idx < Dh * Dout; idx += blockDim.x) {
            int k = idx / Dout, j = idx % Dout;
            float a = 0.f, b = 0.f;
            for (int d = 0; d < Dh; ++d) {
                float wn = Wn5[d * Dout + j];
                a += Wl5[k * Dh + d] * wn;
                b += (Wr5[k * Dh + d] + Ws5[k * Dh + d]) * wn;
            }
            wc5[k * 32 + j] = a;
            wc5[k * 32 + 16 + j] = b;
        }
        for (int j = t; j < Dout; j += blockDim.x) {
            float c0 = 0.f;
            for (int d = 0; d < Dh; ++d) c0 += (bl5[d] + bs5[d]) * Wn5[d * Dout + j];
            c5[j] = c0 + bn5[j];
        }
    }
}

// ---------------- CSR build: atomic-free, XCD-partitioned counting sort ----------------
// Phase 1: per-(slice, range) histogram in LDS -> part[slice][node] (u16).
__global__ __launch_bounds__(256) void hist_partial(
    const int* __restrict__ dst, unsigned short* __restrict__ part)
{
    __shared__ unsigned lds[RANGE];
    int b = blockIdx.x;
    int x = b % NXCD;       // dst range (XCD-locality heuristic: round-robin dispatch)
    int i = b / NXCD;       // edge slice
    int t = threadIdx.x;
    for (int d = t; d < RANGE; d += 256) lds[d] = 0;
    __syncthreads();
    int lo = x * RANGE;
    int e0 = i * SLICE_E;
    int e1 = min(e0 + SLICE_E, Ne);
    for (int e = e0 + t; e < e1; e += 256) {
        int d = dst[e];
        unsigned r = (unsigned)(d - lo);
        if (r < (unsigned)RANGE) atomicAdd(&lds[r], 1u);
    }
    __syncthreads();
    for (int d = t; d < RANGE; d += 256)
        part[(size_t)i * PSTR + lo + d] = (unsigned short)lds[d];
}

// Phase 2: per-node exclusive prefix across slices; total -> cnt.
__global__ void col_prefix(unsigned short* __restrict__ part, unsigned* __restrict__ cnt)
{
    int d = blockIdx.x * blockDim.x + threadIdx.x;
    if (d >= Nn) return;
    unsigned run = 0;
#pragma unroll
    for (int i = 0; i < NSLICE; ++i) {
        size_t idx = (size_t)i * PSTR + d;
        unsigned v = part[idx];
        part[idx] = (unsigned short)run;
        run += v;
    }
    cnt[d] = run;
}

// Phase 3 (scans over cnt -> offs), reused from before.
__global__ void scan_blocksums(const unsigned* __restrict__ cnt, unsigned* __restrict__ bsum, int n) {
    __shared__ unsigned sd[256];
    int b = blockIdx.x, t = threadIdx.x;
    int base = b * 1024;
    unsigned s = 0;
    for (int i = t; i < 1024; i += 256) {
        int idx = base + i;
        if (idx < n) s += cnt[idx];
    }
    sd[t] = s;
    __syncthreads();
    for (int off = 128; off > 0; off >>= 1) {
        if (t < off) sd[t] += sd[t + off];
        __syncthreads();
    }
    if (t == 0) bsum[b] = sd[0];
}

__global__ void scan_bsum(unsigned* __restrict__ bsum, int nb) {
    __shared__ unsigned sh[128];
    int t = threadIdx.x;
    unsigned v = (t < nb) ? bsum[t] : 0u;
    sh[t] = v;
    __syncthreads();
    for (int off = 1; off < 128; off <<= 1) {
        unsigned add = (t >= off) ? sh[t - off] : 0u;
        __syncthreads();
        sh[t] += add;
        __syncthreads();
    }
    if (t < nb) bsum[t] = sh[t] - v;  // exclusive
}

__global__ void scan_final(const unsigned* __restrict__ cnt, const unsigned* __restrict__ bsum,
                           unsigned* __restrict__ offs, int n) {
    __shared__ unsigned wsum[4], woff[4];
    int b = blockIdx.x, t = threadIdx.x;
    int base = b * 1024 + t * 4;
    unsigned v[4];
    unsigned s = 0;
#pragma unroll
    for (int i = 0; i < 4; ++i) {
        int idx = base + i;
        v[i] = (idx < n) ? cnt[idx] : 0u;
        s += v[i];
    }
    unsigned lane = t & 63;
    int w = t >> 6;
    unsigned val = s;
    for (int off = 1; off < 64; off <<= 1) {
        unsigned u = __shfl_up(val, off, 64);
        if (lane >= off) val += u;
    }
    if (lane == 63) wsum[w] = val;
    __syncthreads();
    if (t == 0) {
        unsigned r = 0;
        for (int i = 0; i < 4; ++i) { woff[i] = r; r += wsum[i]; }
    }
    __syncthreads();
    unsigned run = bsum[b] + woff[w] + (val - s);
#pragma unroll
    for (int i = 0; i < 4; ++i) {
        int idx = base + i;
        if (idx < n) {
            offs[idx] = run;
            run += v[i];
            if (idx == n - 1) offs[n] = run;
        }
    }
}

// Phase 4: fill. LDS cursor per node (seeded offs+prefix); LDS atomics only.
// Writes for range x land in one contiguous ~800KB csr segment from blocks b%8==x.
__global__ __launch_bounds__(256) void csr_fill_lds(
    const int* __restrict__ src, const int* __restrict__ dst,
    const unsigned* __restrict__ offs, const unsigned short* __restrict__ part,
    unsigned* __restrict__ csr)
{
    __shared__ unsigned lds[RANGE];
    int b = blockIdx.x;
    int x = b % NXCD;
    int i = b / NXCD;
    int t = threadIdx.x;
    int lo = x * RANGE;
    for (int d = t; d < RANGE; d += 256)
        lds[d] = offs[lo + d] + part[(size_t)i * PSTR + lo + d];
    __syncthreads();
    int e0 = i * SLICE_E;
    int e1 = min(e0 + SLICE_E, Ne);
    for (int e = e0 + t; e < e1; e += 256) {
        int d = dst[e];
        unsigned r = (unsigned)(d - lo);
        if (r < (unsigned)RANGE) {
            unsigned pos = atomicAdd(&lds[r], 1u);
            csr[pos] = (unsigned)src[e];
        }
    }
}

// ---------------- fused (lazy-BN+ReLU) + projection: xa(bf16) = f(x)@A, xb = f(x)@B + c ------
template <int FINt, int FO, bool NORM>
__global__ __launch_bounds__(256) void gemm_kernel(
    const float* __restrict__ xin, const float* __restrict__ stats,
    const float* __restrict__ g, const float* __restrict__ be,
    const float* __restrict__ wc, const float* __restrict__ cvec,
    unsigned short* __restrict__ xa, float* __restrict__ xb)
{
    __shared__ float sscale[Dh], sshift[Dh];
    int t = threadIdx.x;
    if (NORM) {
        if (t < Dh) {
            float mu = stats[t] * (1.0f / Nn);
            float var = stats[32 + t] * (1.0f / Nn) - mu * mu;
            float sc = g[t] * rsqrtf(var + EPSV);
            sscale[t] = sc;
            sshift[t] = be[t] - mu * sc;
        }
        __syncthreads();
    }
    int n = blockIdx.x * blockDim.x + t;
    if (n >= Nn) return;

    float acc[2 * FO];
#pragma unroll
    for (int j = 0; j < 2 * FO; ++j) acc[j] = 0.f;

    const float4* xr = (const float4*)(xin + (size_t)n * FINt);
#pragma unroll
    for (int c = 0; c < FINt / 4; ++c) {
        float4 v = xr[c];
        float xs[4] = {v.x, v.y, v.z, v.w};
        if (NORM) {
#pragma unroll
            for (int kk = 0; kk < 4; ++kk)
                xs[kk] = fmaxf(xs[kk] * sscale[4 * c + kk] + sshift[4 * c + kk], 0.0f);
        }
#pragma unroll
        for (int kk = 0; kk < 4; ++kk) {
            float xk = xs[kk];
            const float* wr = wc + (4 * c + kk) * (2 * FO);  // uniform -> scalar loads
#pragma unroll
            for (int j = 0; j < 2 * FO; ++j) acc[j] = fmaf(xk, wr[j], acc[j]);
        }
    }

    ushort4* xao = (ushort4*)(xa + (size_t)n * FO);
    float4* xbo = (float4*)(xb + (size_t)n * FO);
#pragma unroll
    for (int c = 0; c < FO / 4; ++c) {
        ushort4 o;
        o.x = f2b(acc[4 * c + 0]);
        o.y = f2b(acc[4 * c + 1]);
        o.z = f2b(acc[4 * c + 2]);
        o.w = f2b(acc[4 * c + 3]);
        xao[c] = o;
        float4 p;
        p.x = acc[FO + 4 * c + 0] + cvec[4 * c + 0];
        p.y = acc[FO + 4 * c + 1] + cvec[4 * c + 1];
        p.z = acc[FO + 4 * c + 2] + cvec[4 * c + 2];
        p.w = acc[FO + 4 * c + 3] + cvec[4 * c + 3];
        xbo[c] = p;
    }
}

// ---------------- pull aggregation + combine (+ BN stats) ----------------
// One thread per (node, 4-feature chunk): C = F/4 threads per node.
// Gather table is bf16 (4MB -> L2-resident); 8-deep batched gathers for MLP.
template <int F, bool WITH_STATS>
__global__ __launch_bounds__(256) void pull_kernel(
    const unsigned* __restrict__ offs, const unsigned* __restrict__ csr,
    const unsigned short* __restrict__ xa, const float* __restrict__ xb,
    float* __restrict__ out, float* __restrict__ stats)
{
    constexpr int C = F / 4;
    __shared__ float sstat[2 * F];
    int t = threadIdx.x;
    if (WITH_STATS) {
        if (t < 2 * F) sstat[t] = 0.f;
        __syncthreads();
    }
    int tid = blockIdx.x * blockDim.x + t;
    int n = tid / C;
    int c = tid % C;
    bool act = (n < Nn);
    float4 h = {0.f, 0.f, 0.f, 0.f};
    if (act) {
        unsigned b = offs[n], e = offs[n + 1];
        const unsigned short* base = xa + (size_t)c * 4;
        float4 acc = {0.f, 0.f, 0.f, 0.f};
        unsigned k = b;
        for (; k + 8 <= e; k += 8) {
            unsigned s[8];
#pragma unroll
            for (int i = 0; i < 8; ++i) s[i] = csr[k + i];
            ushort4 v[8];
#pragma unroll
            for (int i = 0; i < 8; ++i) v[i] = *(const ushort4*)(base + (size_t)s[i] * F);
#pragma unroll
            for (int i = 0; i < 8; ++i) {
                acc.x += b2f(v[i].x); acc.y += b2f(v[i].y);
                acc.z += b2f(v[i].z); acc.w += b2f(v[i].w);
            }
        }
        for (; k < e; ++k) {
            unsigned s0 = csr[k];
            ushort4 v = *(const ushort4*)(base + (size_t)s0 * F);
            acc.x += b2f(v.x); acc.y += b2f(v.y); acc.z += b2f(v.z); acc.w += b2f(v.w);
        }
        float inv = 1.0f / fmaxf((float)(e - b), 1.0f);
        float4 xv = *(const float4*)(xb + (size_t)n * F + c * 4);
        h.x = fmaf(acc.x, inv, xv.x);
        h.y = fmaf(acc.y, inv, xv.y);
        h.z = fmaf(acc.z, inv, xv.z);
        h.w = fmaf(acc.w, inv, xv.w);
        *(float4*)(out + (size_t)n * F + c * 4) = h;
    }
    if (WITH_STATS) {
        if (act) {
            atomicAdd(&sstat[c * 4 + 0], h.x);
            atomicAdd(&sstat[c * 4 + 1], h.y);
            atomicAdd(&sstat[c * 4 + 2], h.z);
            atomicAdd(&sstat[c * 4 + 3], h.w);
            atomicAdd(&sstat[F + c * 4 + 0], h.x * h.x);
            atomicAdd(&sstat[F + c * 4 + 1], h.y * h.y);
            atomicAdd(&sstat[F + c * 4 + 2], h.z * h.z);
            atomicAdd(&sstat[F + c * 4 + 3], h.w * h.w);
        }
        __syncthreads();
        if (t < F) {
            atomicAdd(&stats[t], sstat[t]);
        } else if (t < 2 * F) {
            atomicAdd(&stats[32 + (t - F)], sstat[t]);
        }
    }
}

// ---------------- launch ----------------
extern "C" void kernel_launch(void* const* d_in, const int* in_sizes, int n_in,
                              void* d_out, int out_size, void* d_ws, size_t ws_size,
                              hipStream_t stream) {
    const float* x   = (const float*)d_in[0];
    const int* ei    = (const int*)d_in[1];
    const int* esrc  = ei;
    const int* edst  = ei + Ne;
    const float* Wl1 = (const float*)d_in[3];
    const float* bl1 = (const float*)d_in[4];
    const float* Wr1 = (const float*)d_in[5];
    const float* Ws1 = (const float*)d_in[6];
    const float* bs1 = (const float*)d_in[7];
    const float* Wn1 = (const float*)d_in[8];
    const float* bn1 = (const float*)d_in[9];
    const float* g1  = (const float*)d_in[10];
    const float* be1 = (const float*)d_in[11];
    const float* Wlm = (const float*)d_in[12];
    const float* blm = (const float*)d_in[13];
    const float* Wrm = (const float*)d_in[14];
    const float* Wsm = (const float*)d_in[15];
    const float* bsm = (const float*)d_in[16];
    const float* Wnm = (const float*)d_in[17];
    const float* bnm = (const float*)d_in[18];
    const float* gm  = (const float*)d_in[19];
    const float* bem = (const float*)d_in[20];
    const float* Wl5 = (const float*)d_in[21];
    const float* bl5 = (const float*)d_in[22];
    const float* Wr5 = (const float*)d_in[23];
    const float* Ws5 = (const float*)d_in[24];
    const float* bs5 = (const float*)d_in[25];
    const float* Wn5 = (const float*)d_in[26];
    const float* bn5 = (const float*)d_in[27];

    float* ws   = (float*)d_ws;
    unsigned* u = (unsigned*)d_ws;
    float* wc1   = ws + OFF_WC1;
    float* c1    = ws + OFF_C1;
    float* wcm   = ws + OFF_WCM;
    float* cm    = ws + OFF_CM;
    float* wc5   = ws + OFF_WC5;
    float* c5    = ws + OFF_C5;
    float* stats = ws + OFF_ST;
    unsigned* offs = u + OFF_OFFS;
    unsigned* bsum = u + OFF_BSUM;
    unsigned* cnt  = u + OFF_CNT;
    unsigned* csr  = u + OFF_CSR;
    unsigned short* xa = (unsigned short*)(ws + OFF_XA);
    unsigned short* part = (unsigned short*)(ws + OFF_XA);  // dead before gemm1 writes xa/xb
    float* xb = ws + OFF_XB;
    float* hp = ws + OFF_HP;
    float* out = (float*)d_out;

    hipMemsetAsync(stats, 0, 256 * sizeof(float), stream);

    prep_weights<<<5, 256, 0, stream>>>(Wl1, bl1, Wr1, Ws1, bs1, Wn1, bn1,
                                        Wlm, blm, Wrm, Wsm, bsm, Wnm, bnm,
                                        Wl5, bl5, Wr5, Ws5, bs5, Wn5, bn5,
                                        wc1, c1, wcm, cm, wc5, c5);

    // ---- CSR build (atomic-free) ----
    hist_partial<<<NSLICE * NXCD, 256, 0, stream>>>(edst, part);
    col_prefix<<<(Nn + 255) / 256, 256, 0, stream>>>(part, cnt);
    constexpr int NB = (Nn + 1023) / 1024;  // 98
    scan_blocksums<<<NB, 256, 0, stream>>>(cnt, bsum, Nn);
    scan_bsum<<<1, 128, 0, stream>>>(bsum, NB);
    scan_final<<<NB, 256, 0, stream>>>(cnt, bsum, offs, Nn);
    csr_fill_lds<<<NSLICE * NXCD, 256, 0, stream>>>(esrc, edst, offs, part, csr);

    int nblk = (Nn + 255) / 256;                  // 391  (gemm: node per thread)
    int pblk20 = (Nn * 5 + 255) / 256;            // 1954 (pull F=20: 5 thr/node)
    int pblk16 = (Nn * 4 + 255) / 256;            // 1563 (pull F=16: 4 thr/node)

    // layer 1
    gemm_kernel<FINN, Dh, false><<<nblk, 256, 0, stream>>>(x, nullptr, nullptr, nullptr, wc1, c1, xa, xb);
    pull_kernel<Dh, true><<<pblk20, 256, 0, stream>>>(offs, csr, xa, xb, hp, stats + 0);
    // layer 2
    gemm_kernel<Dh, Dh, true><<<nblk, 256, 0, stream>>>(hp, stats + 0, g1, be1, wcm + 0, cm + 0, xa, xb);
    pull_kernel<Dh, true><<<pblk20, 256, 0, stream>>>(offs, csr, xa, xb, hp, stats + 64);
    // layer 3
    gemm_kernel<Dh, Dh, true><<<nblk, 256, 0, stream>>>(hp, stats + 64, gm + 0, bem + 0, wcm + 800, cm + 32, xa, xb);
    pull_kernel<Dh, true><<<pblk20, 256, 0, stream>>>(offs, csr, xa, xb, hp, stats + 128);
    // layer 4
    gemm_kernel<Dh, Dh, true><<<nblk, 256, 0, stream>>>(hp, stats + 128, gm + 20, bem + 20, wcm + 1600, cm + 64, xa, xb);
    pull_kernel<Dh, true><<<pblk20, 256, 0, stream>>>(offs, csr, xa, xb, hp, stats + 192);
    // layer 5 (no BN/ReLU at output; lazy-norm of layer-4 applied here)
    gemm_kernel<Dh, Dout, true><<<nblk, 256, 0, stream>>>(hp, stats + 192, gm + 40, bem + 40, wc5, c5, xa, xb);
    pull_kernel<Dout, false><<<pblk16, 256, 0, stream>>>(offs, csr, xa, xb, out, nullptr);
}

// Round 5
// 462.430 us; speedup vs baseline: 4.3031x; 1.1870x over previous
//
#include <hip/hip_runtime.h>

// ---------------- problem constants ----------------
constexpr int Nn   = 100000;
constexpr int Ne   = 1600000;
constexpr int FINN = 64;
constexpr int Dh   = 20;
constexpr int Dout = 16;
constexpr float EPSV = 1e-5f;

// CSR build: two-pass radix by dst range.
constexpr int NR  = 16;               // dst ranges (buckets)
constexpr int RSZ = Nn / NR;          // 6250 nodes per range (fits 13 bits)
constexpr int NSL = 32;               // slices per range for pass-2 parallelism
constexpr int P1B = 400;              // partition blocks
constexpr int P1E = Ne / P1B;         // 4000 edges per partition block

// ---------------- workspace layout (float units) ----------------
constexpr size_t OFF_WC1  = 0;         // 64*40 combined [A|B] layer1
constexpr size_t OFF_C1   = 2560;      // 32
constexpr size_t OFF_WCM  = 2592;      // 3 * 800 (20*40 each)
constexpr size_t OFF_CM   = 4992;      // 3 * 32
constexpr size_t OFF_WC5  = 5088;      // 20*32
constexpr size_t OFF_C5   = 5728;      // 32
constexpr size_t OFF_ST   = 5760;      // 4 layers * 64 (sum@+0, sumsq@+32)
constexpr size_t OFF_OFFS = 8192;      // u32, N+1 (padded 100352)
constexpr size_t OFF_BSUM = 208896;    // u32, 512
constexpr size_t OFF_CNT  = 209408;    // u32, N (padded 100352)
constexpr size_t OFF_CSR  = 309760;    // u32, Ne  -> ends 1,909,760
constexpr size_t OFF_XA   = 1910784;   // bf16 N*20 used; ebuf (u32, Ne = 6.4MB) aliases (dead before gemm1)
constexpr size_t OFF_XB   = 3910784;   // f32 N*20; part (u16, NR*NSL*RSZ = 6.4MB) aliases (dead before gemm1)
constexpr size_t OFF_HP   = 5910784;   // f32 N*20; bhT/obhT/rbase alias head (dead before pull1)
constexpr size_t OFF_BHT  = OFF_HP;            // u32, NR*P1B = 6400
constexpr size_t OFF_OBHT = OFF_HP + 6400;     // u32, NR*P1B = 6400
constexpr size_t OFF_RB   = OFF_HP + 12800;    // u32, NR+1

// bf16 <-> f32 (bit-exact expand; RNE pack).
__device__ inline unsigned short f2b(float x) {
    unsigned b = __float_as_uint(x);
    return (unsigned short)((b + 0x7FFFu + ((b >> 16) & 1u)) >> 16);
}
__device__ inline float b2f(unsigned short u) {
    return __uint_as_float(((unsigned)u) << 16);
}

// ---------------- weight folding ----------------
// A = Wl@Wn, B = (Wr+Ws)@Wn, c = (bl+bs)@Wn + bn   (per layer)
__global__ void prep_weights(
    const float* __restrict__ Wl1, const float* __restrict__ bl1,
    const float* __restrict__ Wr1, const float* __restrict__ Ws1,
    const float* __restrict__ bs1, const float* __restrict__ Wn1,
    const float* __restrict__ bn1,
    const float* __restrict__ Wlm, const float* __restrict__ blm,
    const float* __restrict__ Wrm, const float* __restrict__ Wsm,
    const float* __restrict__ bsm, const float* __restrict__ Wnm,
    const float* __restrict__ bnm,
    const float* __restrict__ Wl5, const float* __restrict__ bl5,
    const float* __restrict__ Wr5, const float* __restrict__ Ws5,
    const float* __restrict__ bs5, const float* __restrict__ Wn5,
    const float* __restrict__ bn5,
    float* __restrict__ wc1, float* __restrict__ c1,
    float* __restrict__ wcm, float* __restrict__ cm,
    float* __restrict__ wc5, float* __restrict__ c5)
{
    int layer = blockIdx.x;
    int t = threadIdx.x;
    if (layer == 0) {
        for (int idx = t; idx < FINN * Dh; idx += blockDim.x) {
            int k = idx / Dh, j = idx % Dh;
            float a = 0.f, b = 0.f;
            for (int d = 0; d < Dh; ++d) {
                float wn = Wn1[d * Dh + j];
                a += Wl1[k * Dh + d] * wn;
                b += (Wr1[k * Dh + d] + Ws1[k * Dh + d]) * wn;
            }
            wc1[k * 40 + j] = a;
            wc1[k * 40 + 20 + j] = b;
        }
        for (int j = t; j < Dh; j += blockDim.x) {
            float c0 = 0.f;
            for (int d = 0; d < Dh; ++d) c0 += (bl1[d] + bs1[d]) * Wn1[d * Dh + j];
            c1[j] = c0 + bn1[j];
        }
    } else if (layer <= 3) {
        int i = layer - 1;
        const float* Wl = Wlm + i * Dh * Dh;
        const float* Wr = Wrm + i * Dh * Dh;
        const float* Ws = Wsm + i * Dh * Dh;
        const float* Wn = Wnm + i * Dh * Dh;
        const float* bl = blm + i * Dh;
        const float* bs = bsm + i * Dh;
        const float* bn = bnm + i * Dh;
        float* wc = wcm + i * 800;
        float* cc = cm + i * 32;
        for (int idx = t; idx < Dh * Dh; idx += blockDim.x) {
            int k = idx / Dh, j = idx % Dh;
            float a = 0.f, b = 0.f;
            for (int d = 0; d < Dh; ++d) {
                float wn = Wn[d * Dh + j];
                a += Wl[k * Dh + d] * wn;
                b += (Wr[k * Dh + d] + Ws[k * Dh + d]) * wn;
            }
            wc[k * 40 + j] = a;
            wc[k * 40 + 20 + j] = b;
        }
        for (int j = t; j < Dh; j += blockDim.x) {
            float c0 = 0.f;
            for (int d = 0; d < Dh; ++d) c0 += (bl[d] + bs[d]) * Wn[d * Dh + j];
            cc[j] = c0 + bn[j];
        }
    } else {
        for (int idx = t; idx < Dh * Dout; idx += blockDim.x) {
            int k = idx / Dout, j = idx % Dout;
            float a = 0.f, b = 0.f;
            for (int d = 0; d < Dh; ++d) {
                float wn = Wn5[d * Dout + j];
                a += Wl5[k * Dh + d] * wn;
                b += (Wr5[k * Dh + d] + Ws5[k * Dh + d]) * wn;
            }
            wc5[k * 32 + j] = a;
            wc5[k * 32 + 16 + j] = b;
        }
        for (int j = t; j < Dout; j += blockDim.x) {
            float c0 = 0.f;
            for (int d = 0; d < Dh; ++d) c0 += (bl5[d] + bs5[d]) * Wn5[d * Dout + j];
            c5[j] = c0 + bn5[j];
        }
    }
}

// ---------------- CSR build: two-pass radix, no global atomics ----------------
// Pass 1a: per-block histogram over the 16 dst ranges (16 LDS sub-hists to cut contention).
__global__ __launch_bounds__(256) void hist1(const int* __restrict__ dst, unsigned* __restrict__ bhT) {
    __shared__ unsigned h[16 * NR];
    int b = blockIdx.x, t = threadIdx.x;
    for (int i = t; i < 16 * NR; i += 256) h[i] = 0;
    __syncthreads();
    int sub = t & 15;
    int e0 = b * P1E, e1 = min(e0 + P1E, Ne);
    for (int e = e0 + t; e < e1; e += 256) {
        int r = dst[e] / RSZ;
        atomicAdd(&h[sub * NR + r], 1u);
    }
    __syncthreads();
    if (t < NR) {
        unsigned s = 0;
        for (int i = 0; i < 16; ++i) s += h[i * NR + t];
        bhT[t * P1B + b] = s;   // transposed: [range][block]
    }
}

// Pass 1b: per-range exclusive scan over blocks (one wave per range) + range bases.
__global__ __launch_bounds__(1024) void scan1(
    const unsigned* __restrict__ bhT, unsigned* __restrict__ obhT, unsigned* __restrict__ rbase)
{
    __shared__ unsigned rtot[NR];
    int t = threadIdx.x;
    int w = t >> 6, lane = t & 63;
    constexpr int PER = (P1B + 63) / 64;  // 7
    if (w < NR) {
        unsigned v[PER];
        unsigned s = 0;
#pragma unroll
        for (int i = 0; i < PER; ++i) {
            int b = lane * PER + i;
            v[i] = (b < P1B) ? bhT[w * P1B + b] : 0u;
            s += v[i];
        }
        unsigned val = s;
        for (int off = 1; off < 64; off <<= 1) {
            unsigned u = __shfl_up(val, off, 64);
            if (lane >= off) val += u;
        }
        unsigned run = val - s;  // exclusive
#pragma unroll
        for (int i = 0; i < PER; ++i) {
            int b = lane * PER + i;
            if (b < P1B) obhT[w * P1B + b] = run;
            run += v[i];
        }
        if (lane == 63) rtot[w] = val;
    }
    __syncthreads();
    if (t == 0) {
        unsigned base = 0;
        for (int r = 0; r < NR; ++r) { rbase[r] = base; base += rtot[r]; }
        rbase[NR] = base;
    }
}

// Pass 1c: scatter packed (dlow<<17 | src) into range buckets. LDS cursors only.
__global__ __launch_bounds__(256) void scatter1(
    const int* __restrict__ src, const int* __restrict__ dst,
    const unsigned* __restrict__ obhT, const unsigned* __restrict__ rbase,
    unsigned* __restrict__ ebuf)
{
    __shared__ unsigned cur[NR];
    int b = blockIdx.x, t = threadIdx.x;
    if (t < NR) cur[t] = rbase[t] + obhT[t * P1B + b];
    __syncthreads();
    int e0 = b * P1E, e1 = min(e0 + P1E, Ne);
    for (int e = e0 + t; e < e1; e += 256) {
        int d = dst[e];
        int r = d / RSZ;
        unsigned dl = (unsigned)(d - r * RSZ);
        unsigned pos = atomicAdd(&cur[r], 1u);
        ebuf[pos] = (dl << 17) | (unsigned)src[e];
    }
}

// Pass 2a: per-(range,slice) node histogram; all edges in-range (no predicate waste).
__global__ __launch_bounds__(256) void hist2(
    const unsigned* __restrict__ ebuf, const unsigned* __restrict__ rbase,
    unsigned short* __restrict__ part)
{
    __shared__ unsigned h[RSZ];   // 25 KB
    int b = blockIdx.x, t = threadIdx.x;
    int r = b % NR, s = b / NR;
    for (int i = t; i < RSZ; i += 256) h[i] = 0;
    __syncthreads();
    unsigned lo = rbase[r], hi = rbase[r + 1];
    unsigned step = (hi - lo + NSL - 1) / NSL;
    unsigned e0 = lo + (unsigned)s * step;
    unsigned e1 = e0 + step; if (e1 > hi) e1 = hi;
    for (unsigned e = e0 + t; e < e1; e += 256)
        atomicAdd(&h[ebuf[e] >> 17], 1u);
    __syncthreads();
    unsigned short* p = part + (size_t)b * RSZ;
    for (int i = t; i < RSZ; i += 256) p[i] = (unsigned short)h[i];
}

// Pass 2b: per-node exclusive prefix across slices; total degree -> cnt.
__global__ void col_prefix(unsigned short* __restrict__ part, unsigned* __restrict__ cnt) {
    int d = blockIdx.x * blockDim.x + threadIdx.x;
    if (d >= Nn) return;
    int r = d / RSZ, dl = d - r * RSZ;
    unsigned run = 0;
#pragma unroll
    for (int s = 0; s < NSL; ++s) {
        size_t idx = ((size_t)s * NR + r) * RSZ + dl;
        unsigned v = part[idx];
        part[idx] = (unsigned short)run;
        run += v;
    }
    cnt[d] = run;
}

// Pass 3: scans over cnt -> offs (unchanged).
__global__ void scan_blocksums(const unsigned* __restrict__ cnt, unsigned* __restrict__ bsum, int n) {
    __shared__ unsigned sd[256];
    int b = blockIdx.x, t = threadIdx.x;
    int base = b * 1024;
    unsigned s = 0;
    for (int i = t; i < 1024; i += 256) {
        int idx = base + i;
        if (idx < n) s += cnt[idx];
    }
    sd[t] = s;
    __syncthreads();
    for (int off = 128; off > 0; off >>= 1) {
        if (t < off) sd[t] += sd[t + off];
        __syncthreads();
    }
    if (t == 0) bsum[b] = sd[0];
}

__global__ void scan_bsum(unsigned* __restrict__ bsum, int nb) {
    __shared__ unsigned sh[128];
    int t = threadIdx.x;
    unsigned v = (t < nb) ? bsum[t] : 0u;
    sh[t] = v;
    __syncthreads();
    for (int off = 1; off < 128; off <<= 1) {
        unsigned add = (t >= off) ? sh[t - off] : 0u;
        __syncthreads();
        sh[t] += add;
        __syncthreads();
    }
    if (t < nb) bsum[t] = sh[t] - v;  // exclusive
}

__global__ void scan_final(const unsigned* __restrict__ cnt, const unsigned* __restrict__ bsum,
                           unsigned* __restrict__ offs, int n) {
    __shared__ unsigned wsum[4], woff[4];
    int b = blockIdx.x, t = threadIdx.x;
    int base = b * 1024 + t * 4;
    unsigned v[4];
    unsigned s = 0;
#pragma unroll
    for (int i = 0; i < 4; ++i) {
        int idx = base + i;
        v[i] = (idx < n) ? cnt[idx] : 0u;
        s += v[i];
    }
    unsigned lane = t & 63;
    int w = t >> 6;
    unsigned val = s;
    for (int off = 1; off < 64; off <<= 1) {
        unsigned u = __shfl_up(val, off, 64);
        if (lane >= off) val += u;
    }
    if (lane == 63) wsum[w] = val;
    __syncthreads();
    if (t == 0) {
        unsigned r = 0;
        for (int i = 0; i < 4; ++i) { woff[i] = r; r += wsum[i]; }
    }
    __syncthreads();
    unsigned run = bsum[b] + woff[w] + (val - s);
#pragma unroll
    for (int i = 0; i < 4; ++i) {
        int idx = base + i;
        if (idx < n) {
            offs[idx] = run;
            run += v[i];
            if (idx == n - 1) offs[n] = run;
        }
    }
}

// Pass 4: fill. LDS cursor per node (seeded offs+part); LDS atomics only; src comes packed.
__global__ __launch_bounds__(256) void fill2(
    const unsigned* __restrict__ ebuf, const unsigned* __restrict__ rbase,
    const unsigned* __restrict__ offs, const unsigned short* __restrict__ part,
    unsigned* __restrict__ csr)
{
    __shared__ unsigned cur[RSZ];   // 25 KB
    int b = blockIdx.x, t = threadIdx.x;
    int r = b % NR, s = b / NR;
    int lon = r * RSZ;
    const unsigned short* p = part + (size_t)b * RSZ;
    for (int i = t; i < RSZ; i += 256)
        cur[i] = offs[lon + i] + p[i];
    __syncthreads();
    unsigned lo = rbase[r], hi = rbase[r + 1];
    unsigned step = (hi - lo + NSL - 1) / NSL;
    unsigned e0 = lo + (unsigned)s * step;
    unsigned e1 = e0 + step; if (e1 > hi) e1 = hi;
    for (unsigned e = e0 + t; e < e1; e += 256) {
        unsigned v = ebuf[e];
        unsigned pos = atomicAdd(&cur[v >> 17], 1u);
        csr[pos] = v & 0x1FFFFu;
    }
}

// ---------------- fused (lazy-BN+ReLU) + projection: xa(bf16) = f(x)@A, xb = f(x)@B + c ------
template <int FINt, int FO, bool NORM>
__global__ __launch_bounds__(256) void gemm_kernel(
    const float* __restrict__ xin, const float* __restrict__ stats,
    const float* __restrict__ g, const float* __restrict__ be,
    const float* __restrict__ wc, const float* __restrict__ cvec,
    unsigned short* __restrict__ xa, float* __restrict__ xb)
{
    __shared__ float sscale[Dh], sshift[Dh];
    int t = threadIdx.x;
    if (NORM) {
        if (t < Dh) {
            float mu = stats[t] * (1.0f / Nn);
            float var = stats[32 + t] * (1.0f / Nn) - mu * mu;
            float sc = g[t] * rsqrtf(var + EPSV);
            sscale[t] = sc;
            sshift[t] = be[t] - mu * sc;
        }
        __syncthreads();
    }
    int n = blockIdx.x * blockDim.x + t;
    if (n >= Nn) return;

    float acc[2 * FO];
#pragma unroll
    for (int j = 0; j < 2 * FO; ++j) acc[j] = 0.f;

    const float4* xr = (const float4*)(xin + (size_t)n * FINt);
#pragma unroll
    for (int c = 0; c < FINt / 4; ++c) {
        float4 v = xr[c];
        float xs[4] = {v.x, v.y, v.z, v.w};
        if (NORM) {
#pragma unroll
            for (int kk = 0; kk < 4; ++kk)
                xs[kk] = fmaxf(xs[kk] * sscale[4 * c + kk] + sshift[4 * c + kk], 0.0f);
        }
#pragma unroll
        for (int kk = 0; kk < 4; ++kk) {
            float xk = xs[kk];
            const float* wr = wc + (4 * c + kk) * (2 * FO);  // uniform -> scalar loads
#pragma unroll
            for (int j = 0; j < 2 * FO; ++j) acc[j] = fmaf(xk, wr[j], acc[j]);
        }
    }

    ushort4* xao = (ushort4*)(xa + (size_t)n * FO);
    float4* xbo = (float4*)(xb + (size_t)n * FO);
#pragma unroll
    for (int c = 0; c < FO / 4; ++c) {
        ushort4 o;
        o.x = f2b(acc[4 * c + 0]);
        o.y = f2b(acc[4 * c + 1]);
        o.z = f2b(acc[4 * c + 2]);
        o.w = f2b(acc[4 * c + 3]);
        xao[c] = o;
        float4 p;
        p.x = acc[FO + 4 * c + 0] + cvec[4 * c + 0];
        p.y = acc[FO + 4 * c + 1] + cvec[4 * c + 1];
        p.z = acc[FO + 4 * c + 2] + cvec[4 * c + 2];
        p.w = acc[FO + 4 * c + 3] + cvec[4 * c + 3];
        xbo[c] = p;
    }
}

// ---------------- pull aggregation + combine (+ BN stats) ----------------
// One thread per (node, 4-feature chunk): C = F/4 threads per node.
// Gather table is bf16 (4MB -> L2-resident); 8-deep batched gathers for MLP.
template <int F, bool WITH_STATS>
__global__ __launch_bounds__(256) void pull_kernel(
    const unsigned* __restrict__ offs, const unsigned* __restrict__ csr,
    const unsigned short* __restrict__ xa, const float* __restrict__ xb,
    float* __restrict__ out, float* __restrict__ stats)
{
    constexpr int C = F / 4;
    __shared__ float sstat[2 * F];
    int t = threadIdx.x;
    if (WITH_STATS) {
        if (t < 2 * F) sstat[t] = 0.f;
        __syncthreads();
    }
    int tid = blockIdx.x * blockDim.x + t;
    int n = tid / C;
    int c = tid % C;
    bool act = (n < Nn);
    float4 h = {0.f, 0.f, 0.f, 0.f};
    if (act) {
        unsigned b = offs[n], e = offs[n + 1];
        const unsigned short* base = xa + (size_t)c * 4;
        float4 acc = {0.f, 0.f, 0.f, 0.f};
        unsigned k = b;
        for (; k + 8 <= e; k += 8) {
            unsigned s[8];
#pragma unroll
            for (int i = 0; i < 8; ++i) s[i] = csr[k + i];
            ushort4 v[8];
#pragma unroll
            for (int i = 0; i < 8; ++i) v[i] = *(const ushort4*)(base + (size_t)s[i] * F);
#pragma unroll
            for (int i = 0; i < 8; ++i) {
                acc.x += b2f(v[i].x); acc.y += b2f(v[i].y);
                acc.z += b2f(v[i].z); acc.w += b2f(v[i].w);
            }
        }
        for (; k < e; ++k) {
            unsigned s0 = csr[k];
            ushort4 v = *(const ushort4*)(base + (size_t)s0 * F);
            acc.x += b2f(v.x); acc.y += b2f(v.y); acc.z += b2f(v.z); acc.w += b2f(v.w);
        }
        float inv = 1.0f / fmaxf((float)(e - b), 1.0f);
        float4 xv = *(const float4*)(xb + (size_t)n * F + c * 4);
        h.x = fmaf(acc.x, inv, xv.x);
        h.y = fmaf(acc.y, inv, xv.y);
        h.z = fmaf(acc.z, inv, xv.z);
        h.w = fmaf(acc.w, inv, xv.w);
        *(float4*)(out + (size_t)n * F + c * 4) = h;
    }
    if (WITH_STATS) {
        if (act) {
            atomicAdd(&sstat[c * 4 + 0], h.x);
            atomicAdd(&sstat[c * 4 + 1], h.y);
            atomicAdd(&sstat[c * 4 + 2], h.z);
            atomicAdd(&sstat[c * 4 + 3], h.w);
            atomicAdd(&sstat[F + c * 4 + 0], h.x * h.x);
            atomicAdd(&sstat[F + c * 4 + 1], h.y * h.y);
            atomicAdd(&sstat[F + c * 4 + 2], h.z * h.z);
            atomicAdd(&sstat[F + c * 4 + 3], h.w * h.w);
        }
        __syncthreads();
        if (t < F) {
            atomicAdd(&stats[t], sstat[t]);
        } else if (t < 2 * F) {
            atomicAdd(&stats[32 + (t - F)], sstat[t]);
        }
    }
}

// ---------------- launch ----------------
extern "C" void kernel_launch(void* const* d_in, const int* in_sizes, int n_in,
                              void* d_out, int out_size, void* d_ws, size_t ws_size,
                              hipStream_t stream) {
    const float* x   = (const float*)d_in[0];
    const int* ei    = (const int*)d_in[1];
    const int* esrc  = ei;
    const int* edst  = ei + Ne;
    const float* Wl1 = (const float*)d_in[3];
    const float* bl1 = (const float*)d_in[4];
    const float* Wr1 = (const float*)d_in[5];
    const float* Ws1 = (const float*)d_in[6];
    const float* bs1 = (const float*)d_in[7];
    const float* Wn1 = (const float*)d_in[8];
    const float* bn1 = (const float*)d_in[9];
    const float* g1  = (const float*)d_in[10];
    const float* be1 = (const float*)d_in[11];
    const float* Wlm = (const float*)d_in[12];
    const float* blm = (const float*)d_in[13];
    const float* Wrm = (const float*)d_in[14];
    const float* Wsm = (const float*)d_in[15];
    const float* bsm = (const float*)d_in[16];
    const float* Wnm = (const float*)d_in[17];
    const float* bnm = (const float*)d_in[18];
    const float* gm  = (const float*)d_in[19];
    const float* bem = (const float*)d_in[20];
    const float* Wl5 = (const float*)d_in[21];
    const float* bl5 = (const float*)d_in[22];
    const float* Wr5 = (const float*)d_in[23];
    const float* Ws5 = (const float*)d_in[24];
    const float* bs5 = (const float*)d_in[25];
    const float* Wn5 = (const float*)d_in[26];
    const float* bn5 = (const float*)d_in[27];

    float* ws   = (float*)d_ws;
    unsigned* u = (unsigned*)d_ws;
    float* wc1   = ws + OFF_WC1;
    float* c1    = ws + OFF_C1;
    float* wcm   = ws + OFF_WCM;
    float* cm    = ws + OFF_CM;
    float* wc5   = ws + OFF_WC5;
    float* c5    = ws + OFF_C5;
    float* stats = ws + OFF_ST;
    unsigned* offs = u + OFF_OFFS;
    unsigned* bsum = u + OFF_BSUM;
    unsigned* cnt  = u + OFF_CNT;
    unsigned* csr  = u + OFF_CSR;
    unsigned short* xa = (unsigned short*)(ws + OFF_XA);
    unsigned* ebuf = u + OFF_XA;                           // aliases xa region (dead before gemm1)
    float* xb = ws + OFF_XB;
    unsigned short* part = (unsigned short*)(ws + OFF_XB); // aliases xb region (dead before gemm1)
    float* hp = ws + OFF_HP;
    unsigned* bhT  = u + OFF_BHT;                          // alias hp head (dead before pull1)
    unsigned* obhT = u + OFF_OBHT;
    unsigned* rbase = u + OFF_RB;
    float* out = (float*)d_out;

    hipMemsetAsync(stats, 0, 256 * sizeof(float), stream);

    prep_weights<<<5, 256, 0, stream>>>(Wl1, bl1, Wr1, Ws1, bs1, Wn1, bn1,
                                        Wlm, blm, Wrm, Wsm, bsm, Wnm, bnm,
                                        Wl5, bl5, Wr5, Ws5, bs5, Wn5, bn5,
                                        wc1, c1, wcm, cm, wc5, c5);

    // ---- CSR build (two-pass radix, no global atomics) ----
    hist1<<<P1B, 256, 0, stream>>>(edst, bhT);
    scan1<<<1, 1024, 0, stream>>>(bhT, obhT, rbase);
    scatter1<<<P1B, 256, 0, stream>>>(esrc, edst, obhT, rbase, ebuf);
    hist2<<<NR * NSL, 256, 0, stream>>>(ebuf, rbase, part);
    col_prefix<<<(Nn + 255) / 256, 256, 0, stream>>>(part, cnt);
    constexpr int NB = (Nn + 1023) / 1024;  // 98
    scan_blocksums<<<NB, 256, 0, stream>>>(cnt, bsum, Nn);
    scan_bsum<<<1, 128, 0, stream>>>(bsum, NB);
    scan_final<<<NB, 256, 0, stream>>>(cnt, bsum, offs, Nn);
    fill2<<<NR * NSL, 256, 0, stream>>>(ebuf, rbase, offs, part, csr);

    int nblk = (Nn + 255) / 256;                  // 391  (gemm: node per thread)
    int pblk20 = (Nn * 5 + 255) / 256;            // 1954 (pull F=20: 5 thr/node)
    int pblk16 = (Nn * 4 + 255) / 256;            // 1563 (pull F=16: 4 thr/node)

    // layer 1
    gemm_kernel<FINN, Dh, false><<<nblk, 256, 0, stream>>>(x, nullptr, nullptr, nullptr, wc1, c1, xa, xb);
    pull_kernel<Dh, true><<<pblk20, 256, 0, stream>>>(offs, csr, xa, xb, hp, stats + 0);
    // layer 2
    gemm_kernel<Dh, Dh, true><<<nblk, 256, 0, stream>>>(hp, stats + 0, g1, be1, wcm + 0, cm + 0, xa, xb);
    pull_kernel<Dh, true><<<pblk20, 256, 0, stream>>>(offs, csr, xa, xb, hp, stats + 64);
    // layer 3
    gemm_kernel<Dh, Dh, true><<<nblk, 256, 0, stream>>>(hp, stats + 64, gm + 0, bem + 0, wcm + 800, cm + 32, xa, xb);
    pull_kernel<Dh, true><<<pblk20, 256, 0, stream>>>(offs, csr, xa, xb, hp, stats + 128);
    // layer 4
    gemm_kernel<Dh, Dh, true><<<nblk, 256, 0, stream>>>(hp, stats + 128, gm + 20, bem + 20, wcm + 1600, cm + 64, xa, xb);
    pull_kernel<Dh, true><<<pblk20, 256, 0, stream>>>(offs, csr, xa, xb, hp, stats + 192);
    // layer 5 (no BN/ReLU at output; lazy-norm of layer-4 applied here)
    gemm_kernel<Dh, Dout, true><<<nblk, 256, 0, stream>>>(hp, stats + 192, gm + 40, bem + 40, wc5, c5, xa, xb);
    pull_kernel<Dout, false><<<pblk16, 256, 0, stream>>>(offs, csr, xa, xb, out, nullptr);
}